// Round 10
// baseline (1724.286 us; speedup 1.0000x reference)
//
#include <hip/hip_runtime.h>
#include <hip/hip_bf16.h>
#include <math.h>

#define VSZ 1056
#define DD 320
#define NH 5
#define HD 64
#define FF 864
#define NL 6
#define NLOOPS 8
#define BB 8
#define SL 2048
#define KK 1638          // int(2048 * 0.8)
#define EPSF 1e-6f

typedef _Float16 f16x8 __attribute__((ext_vector_type(8)));
typedef _Float16 f16x4 __attribute__((ext_vector_type(4)));
typedef float floatx16 __attribute__((ext_vector_type(16)));

__device__ inline void gll16(const void* g, void* l) {
    __builtin_amdgcn_global_load_lds((const __attribute__((address_space(1))) void*)g,
                                     (__attribute__((address_space(3))) void*)l, 16, 0, 0);
}

// ======================= cast fp32 -> fp16 (x4) =======================
__global__ __launch_bounds__(256) void cast4_kernel(const float* __restrict__ s,
        _Float16* __restrict__ d, int n4) {
    int i = blockIdx.x * 256 + threadIdx.x;
    if (i >= n4) return;
    float4 v = ((const float4*)s)[i];
    f16x4 o = { (_Float16)v.x, (_Float16)v.y, (_Float16)v.z, (_Float16)v.w };
    *(f16x4*)(d + (size_t)i * 4) = o;
}

// ======================= RoPE table init (once): tab[s][j] = (cos, sin)(s * freq_j) ===
__global__ __launch_bounds__(256) void rope_init_kernel(float2* __restrict__ tab) {
    int i = blockIdx.x * 256 + threadIdx.x;          // over SL*32
    int s = i >> 5, j = i & 31;
    float freq = exp2f(-(float)j * 0.4152410118609203f);   // 10000^(-j/32)
    float ang = (float)s * freq;
    tab[i] = make_float2(cosf(ang), sinf(ang));
}

// ======================= embed =======================
__global__ __launch_bounds__(256) void embed_kernel(const int* __restrict__ ids,
        const int* __restrict__ iter, const float* __restrict__ emb,
        const float* __restrict__ iter_emb, float* __restrict__ x) {
    int i = blockIdx.x * 256 + threadIdx.x;          // over B*S*D
    int d = i % DD, bs = i / DD;
    float v = emb[(size_t)ids[bs] * DD + d];
    int it = iter[0];
    if (it < NLOOPS) v += iter_emb[it * DD + d];
    x[i] = v;
}

// ======================= rmsnorm (1 wave per row, D=320 -> 5/lane) =======================
template<typename OT>
__global__ __launch_bounds__(256) void rmsnorm_kernel(const float* __restrict__ x,
        const float* __restrict__ w, OT* __restrict__ out, int nrows) {
    int row = blockIdx.x * 4 + (threadIdx.x >> 6);
    int lane = threadIdx.x & 63;
    if (row >= nrows) return;
    const float* xr = x + (size_t)row * DD;
    float v[5]; float ss = 0.f;
#pragma unroll
    for (int i = 0; i < 5; ++i) { v[i] = xr[lane + i * 64]; ss += v[i] * v[i]; }
#pragma unroll
    for (int o = 32; o > 0; o >>= 1) ss += __shfl_xor(ss, o);
    float r = rsqrtf(ss * (1.f / DD) + EPSF);
    OT* orow = out + (size_t)row * DD;
#pragma unroll
    for (int i = 0; i < 5; ++i) orow[lane + i * 64] = (OT)(w[lane + i * 64] * v[i] * r);
}

// gather selected tokens + rmsnorm -> fp16
__global__ __launch_bounds__(256) void gather_rmsnorm_kernel(const float* __restrict__ x,
        const int* __restrict__ tkidx, const float* __restrict__ w,
        _Float16* __restrict__ out, int nrows) {
    int row = blockIdx.x * 4 + (threadIdx.x >> 6);
    int lane = threadIdx.x & 63;
    if (row >= nrows) return;
    int b = row / KK;
    int t = tkidx[row];
    const float* xr = x + ((size_t)b * SL + t) * DD;
    float v[5]; float ss = 0.f;
#pragma unroll
    for (int i = 0; i < 5; ++i) { v[i] = xr[lane + i * 64]; ss += v[i] * v[i]; }
#pragma unroll
    for (int o = 32; o > 0; o >>= 1) ss += __shfl_xor(ss, o);
    float r = rsqrtf(ss * (1.f / DD) + EPSF);
    _Float16* orow = out + (size_t)row * DD;
#pragma unroll
    for (int i = 0; i < 5; ++i) orow[lane + i * 64] = (_Float16)(w[lane + i * 64] * v[i] * r);
}

// ======================= router: sigmoid(x . rw) =======================
__global__ __launch_bounds__(256) void router_kernel(const float* __restrict__ x,
        const float* __restrict__ rw, float* __restrict__ probs, int nrows) {
    int row = blockIdx.x * 4 + (threadIdx.x >> 6);
    int lane = threadIdx.x & 63;
    if (row >= nrows) return;
    const float* xr = x + (size_t)row * DD;
    float ss = 0.f;
#pragma unroll
    for (int i = 0; i < 5; ++i) ss += xr[lane + i * 64] * rw[lane + i * 64];
#pragma unroll
    for (int o = 32; o > 0; o >>= 1) ss += __shfl_xor(ss, o);
    if (lane == 0) probs[row] = 1.f / (1.f + __expf(-ss));
}

// ======================= top-k: radix select on packed (probbits<<32 | 2047-i) ===========
__global__ __launch_bounds__(1024) void topk_kernel(const float* __restrict__ probs,
        int* __restrict__ tkidx, float* __restrict__ tkprob) {
    __shared__ int hist[256];
    __shared__ int scn[256];
    __shared__ int outc;
    __shared__ int s_digit, s_rem;
    int b = blockIdx.x, tid = threadIdx.x;
    unsigned long long k0, k1;
    {
        unsigned int f0 = __float_as_uint(probs[b * SL + tid]);
        unsigned int f1 = __float_as_uint(probs[b * SL + tid + 1024]);
        k0 = ((unsigned long long)f0 << 32) | (unsigned int)(2047 - tid);
        k1 = ((unsigned long long)f1 << 32) | (unsigned int)(2047 - (tid + 1024));
    }
    if (tid == 0) outc = 0;
    unsigned long long prefix = 0, pmask = 0;
    int target = KK;
    for (int shift = 56; shift >= 0; shift -= 8) {
        if (tid < 256) hist[tid] = 0;
        __syncthreads();
        bool a0 = (k0 & pmask) == prefix;
        bool a1 = (k1 & pmask) == prefix;
        int d0 = (int)((k0 >> shift) & 255);
        int d1 = (int)((k1 >> shift) & 255);
        if (a0) atomicAdd(&hist[d0], 1);
        if (a1) atomicAdd(&hist[d1], 1);
        __syncthreads();
        if (tid < 64) {                       // wave 0: suffix scan of 256 bins
            int h0 = hist[tid * 4], h1 = hist[tid * 4 + 1];
            int h2 = hist[tid * 4 + 2], h3 = hist[tid * 4 + 3];
            int s3 = h3, s2 = h2 + s3, s1 = h1 + s2, s0 = h0 + s1;
            int s = s0;
#pragma unroll
            for (int off = 1; off < 64; off <<= 1) {
                int v = __shfl_down(s, off);
                if (tid + off >= 64) v = 0;
                s += v;
            }
            int A = s - s0;                   // sum of later lanes' bins
            scn[tid * 4]     = s0 + A;
            scn[tid * 4 + 1] = s1 + A;
            scn[tid * 4 + 2] = s2 + A;
            scn[tid * 4 + 3] = s3 + A;
        }
        __syncthreads();
        if (tid < 256 && hist[tid] > 0) {
            int S = scn[tid];                 // count digit >= tid
            int Sgt = S - hist[tid];          // count digit >  tid
            if (Sgt < target && target <= S) { s_digit = tid; s_rem = target - Sgt; }
        }
        __syncthreads();
        int dsel = s_digit, rem = s_rem;
        bool full = (rem == hist[dsel]);
        if (a0 && (d0 > dsel || (full && d0 == dsel))) {
            int s = atomicAdd(&outc, 1);
            tkidx[b * KK + s] = 2047 - (int)(k0 & 0xffffffffu);
            tkprob[b * KK + s] = __uint_as_float((unsigned int)(k0 >> 32));
        }
        if (a1 && (d1 > dsel || (full && d1 == dsel))) {
            int s = atomicAdd(&outc, 1);
            tkidx[b * KK + s] = 2047 - (int)(k1 & 0xffffffffu);
            tkprob[b * KK + s] = __uint_as_float((unsigned int)(k1 >> 32));
        }
        if (full) break;
        target = rem;
        prefix |= ((unsigned long long)dsel) << shift;
        pmask  |= ((unsigned long long)255) << shift;
        __syncthreads();
    }
}

// ======================= prep: RoPE (table-based), Q scaled by log2e/8, K/V tiled ======
__global__ __launch_bounds__(256) void prep_kernel(const _Float16* __restrict__ qkv,
        const float2* __restrict__ ropet,
        _Float16* __restrict__ Qh, _Float16* __restrict__ Kt, _Float16* __restrict__ Vt) {
    __shared__ _Float16 vt[64][72];
    int tid = threadIdx.x;
    int t = blockIdx.x, h = blockIdx.y, b = blockIdx.z;
    int bh = b * NH + h;
    int c = tid >> 5;            // d-chunk 0..7
    int slb = tid & 31;
    const float QS = 0.125f * 1.44269504088896341f;   // 1/sqrt(HD) folded with log2(e)
#pragma unroll
    for (int half = 0; half < 2; ++half) {
        int sl = half * 32 + slb;
        int s = t * 64 + sl;
        size_t rbase = ((size_t)(b * SL + s) * 3) * (NH * 64) + h * 64;
        f16x8 qv = *(const f16x8*)(qkv + rbase + c * 8);
        f16x8 qp = *(const f16x8*)(qkv + rbase + (c ^ 4) * 8);
        f16x8 kv = *(const f16x8*)(qkv + rbase + NH * 64 + c * 8);
        f16x8 kp = *(const f16x8*)(qkv + rbase + NH * 64 + (c ^ 4) * 8);
        f16x8 vv = *(const f16x8*)(qkv + rbase + 2 * NH * 64 + c * 8);
        const float2* rp = ropet + (size_t)s * 32 + (c & 3) * 8;
        f16x8 qo, ko;
#pragma unroll
        for (int j = 0; j < 8; ++j) {
            int d = c * 8 + j;
            float2 cs = rp[j];
            float cc = cs.x, sn = cs.y;
            float a = (float)qv[j], p = (float)qp[j];
            float ka = (float)kv[j], kb2 = (float)kp[j];
            float qr = (d < 32) ? a * cc - p * sn : a * cc + p * sn;
            float kr = (d < 32) ? ka * cc - kb2 * sn : ka * cc + kb2 * sn;
            qo[j] = (_Float16)(qr * QS);
            ko[j] = (_Float16)kr;
        }
        *(f16x8*)(Qh + ((size_t)bh * SL + s) * 64 + c * 8) = qo;
        *(f16x8*)(Kt + (((size_t)bh * 32 + t) * 8 + c) * 512 + sl * 8) = ko;
        *(f16x8*)(&vt[sl][c * 8]) = vv;
    }
    __syncthreads();
#pragma unroll
    for (int gg = 0; gg < 2; ++gg) {
        int oo = tid * 16 + gg * 8;
        int kc = oo >> 9;            // storage kc8: 0..7
        int d = (oo >> 3) & 63;
        f16x8 vo;
#pragma unroll
        for (int j = 0; j < 8; ++j) {
            int key = (kc >> 1) * 16 + (j & 3) + 8 * (j >> 2) + 4 * (kc & 1);
            vo[j] = vt[key][d];
        }
        *(f16x8*)(Vt + (((size_t)bh * 32 + t) * 8 + kc) * 512 + d * 8) = vo;
    }
}

// ======= attention v6: WAVE-INDEPENDENT flash. Each wave owns one 32-query tile and
// walks ALL its key-tiles (no split-K, no barriers, no LDS, no idle waves, no combine).
// Block = 4 consecutive q-tiles of one head, longest-first; XCD-chunked heads.
// Operands direct from L2 in fragment layout; exp2 softmax w/ defer-max; max3-tree
// tile max; zero-shuffle P->B operand (V key-permuted in prep); direct 2B output scatter.
__global__ __launch_bounds__(256) void attn_mfma(const _Float16* __restrict__ Qh,
        const _Float16* __restrict__ Kt, const _Float16* __restrict__ Vt,
        _Float16* __restrict__ attn_out) {
    int tid = threadIdx.x;
    int w = tid >> 6;
    int lane = tid & 63;
    int l31 = lane & 31, h5 = lane >> 5;
    // job decode: g&7 -> XCD slot (owns 5 heads); block j gets wave-jobs 4j..4j+3,
    // all same head (4 | 64); qt longest-first.
    int g = blockIdx.x;
    int j = g >> 3;
    int job = j * 4 + w;                 // 0..319 within XCD slot
    int bh = (g & 7) + 8 * (job >> 6);   // 0..39
    int qt = 63 - (job & 63);
    int b = bh / NH, h = bh % NH;
    int nt = (qt >> 1) + 1;
    int qw = qt * 32;
    int myq = qw + l31;

    f16x8 qf[4];
    const _Float16* qrow = Qh + ((size_t)bh * SL + myq) * 64;
#pragma unroll
    for (int kd = 0; kd < 4; ++kd) qf[kd] = *(const f16x8*)(qrow + kd * 16 + h5 * 8);

    const _Float16* Kb = Kt + (size_t)bh * 32 * 4096;
    const _Float16* Vb = Vt + (size_t)bh * 32 * 4096;

    floatx16 O0, O1;
#pragma unroll
    for (int r = 0; r < 16; ++r) { O0[r] = 0.f; O1[r] = 0.f; }
    float m = -INFINITY, l = 0.f;

    for (int t = 0; t < nt; ++t) {
        const _Float16* kb = Kb + (size_t)t * 4096;
        const _Float16* vb = Vb + (size_t)t * 4096;
        f16x8 a0[4], a1[4], v0[4], v1[4];
#pragma unroll
        for (int kd = 0; kd < 4; ++kd) {
            int off = (kd * 2 + h5) * 512 + l31 * 8;
            a0[kd] = *(const f16x8*)(kb + off);
            a1[kd] = *(const f16x8*)(kb + off + 256);
        }
#pragma unroll
        for (int kc = 0; kc < 4; ++kc) {
            int off = (kc * 2 + h5) * 512 + l31 * 8;
            v0[kc] = *(const f16x8*)(vb + off);
            v1[kc] = *(const f16x8*)(vb + off + 256);
        }
        floatx16 S0, S1;
#pragma unroll
        for (int r = 0; r < 16; ++r) { S0[r] = 0.f; S1[r] = 0.f; }
#pragma unroll
        for (int kd = 0; kd < 4; ++kd) {
            S0 = __builtin_amdgcn_mfma_f32_32x32x16_f16(a0[kd], qf[kd], S0, 0, 0, 0);
            S1 = __builtin_amdgcn_mfma_f32_32x32x16_f16(a1[kd], qf[kd], S1, 0, 0, 0);
        }
        int t0 = t * 64;
        if (t0 + 63 > qw) {                  // diagonal tile: causal mask
#pragma unroll
            for (int r = 0; r < 16; ++r) {
                int key = t0 + (r & 3) + 8 * (r >> 2) + 4 * h5;
                if (key > myq) S0[r] = -INFINITY;
                if (key + 32 > myq) S1[r] = -INFINITY;
            }
        }
        // tile max via v_max3-fusable triple tree (31 -> ~17 VALU ops)
        float r0 = fmaxf(fmaxf(S0[0], S0[1]), S0[2]);
        float r1 = fmaxf(fmaxf(S0[3], S0[4]), S0[5]);
        float r2 = fmaxf(fmaxf(S0[6], S0[7]), S0[8]);
        float r3 = fmaxf(fmaxf(S0[9], S0[10]), S0[11]);
        float r4 = fmaxf(fmaxf(S0[12], S0[13]), S0[14]);
        float r5 = fmaxf(fmaxf(S0[15], S1[0]), S1[1]);
        float r6 = fmaxf(fmaxf(S1[2], S1[3]), S1[4]);
        float r7 = fmaxf(fmaxf(S1[5], S1[6]), S1[7]);
        float r8 = fmaxf(fmaxf(S1[8], S1[9]), S1[10]);
        float r9 = fmaxf(fmaxf(S1[11], S1[12]), S1[13]);
        float ra = fmaxf(S1[14], S1[15]);
        float s0 = fmaxf(fmaxf(r0, r1), r2);
        float s1 = fmaxf(fmaxf(r3, r4), r5);
        float s2 = fmaxf(fmaxf(r6, r7), r8);
        float s3 = fmaxf(r9, ra);
        float tmax = fmaxf(fmaxf(fmaxf(s0, s1), s2), s3);
        tmax = fmaxf(tmax, __shfl_xor(tmax, 32));
        if (__any(tmax > m + 8.f)) {         // defer-max (T13)
            float mnew = fmaxf(m, tmax);
            float alpha = exp2f(m - mnew);
            l *= alpha; O0 *= alpha; O1 *= alpha; m = mnew;
        }
        float P0[16], P1[16]; float psum = 0.f;
#pragma unroll
        for (int r = 0; r < 16; ++r) { P0[r] = exp2f(S0[r] - m); psum += P0[r]; }
#pragma unroll
        for (int r = 0; r < 16; ++r) { P1[r] = exp2f(S1[r] - m); psum += P1[r]; }
        psum += __shfl_xor(psum, 32);
        l += psum;
        // PV: straight register-run P (V key-permuted to match). 16 cvt_pkrtz, 0 shuffles.
#pragma unroll
        for (int sub = 0; sub < 2; ++sub) {
            const float* P = sub ? P1 : P0;
#pragma unroll
            for (int kc = 0; kc < 2; ++kc) {
                auto q01 = __builtin_amdgcn_cvt_pkrtz(P[kc * 8 + 0], P[kc * 8 + 1]);
                auto q23 = __builtin_amdgcn_cvt_pkrtz(P[kc * 8 + 2], P[kc * 8 + 3]);
                auto q45 = __builtin_amdgcn_cvt_pkrtz(P[kc * 8 + 4], P[kc * 8 + 5]);
                auto q67 = __builtin_amdgcn_cvt_pkrtz(P[kc * 8 + 6], P[kc * 8 + 7]);
                f16x8 pf;
                pf[0] = (_Float16)q01[0]; pf[1] = (_Float16)q01[1];
                pf[2] = (_Float16)q23[0]; pf[3] = (_Float16)q23[1];
                pf[4] = (_Float16)q45[0]; pf[5] = (_Float16)q45[1];
                pf[6] = (_Float16)q67[0]; pf[7] = (_Float16)q67[1];
                int ksg = sub * 2 + kc;
                O0 = __builtin_amdgcn_mfma_f32_32x32x16_f16(v0[ksg], pf, O0, 0, 0, 0);
                O1 = __builtin_amdgcn_mfma_f32_32x32x16_f16(v1[ksg], pf, O1, 0, 0, 0);
            }
        }
    }
    // -------- direct output (per-wave complete; no combine) --------
    float linv = 1.f / l;
    _Float16* orow = attn_out + ((size_t)(b * SL + myq)) * DD + h * 64;
#pragma unroll
    for (int r = 0; r < 16; ++r) {
        int dl = (r & 3) + 8 * (r >> 2) + 4 * h5;
        orow[dl] = (_Float16)(O0[r] * linv);
        orow[dl + 32] = (_Float16)(O1[r] * linv);
    }
}

// =========== qkv GEMM: 64x128 tile (4 MFMA + 3 staging calls per barrier) ===========
__global__ __launch_bounds__(256) void gemm_qkv(const _Float16* __restrict__ A,
        const _Float16* __restrict__ W, _Float16* __restrict__ Ch,
        int M, int N, int K, int nn_tiles) {
    __shared__ __attribute__((aligned(16))) _Float16 As[2][2048];   // [buf][kc0..3][64][8]
    __shared__ __attribute__((aligned(16))) _Float16 Ws[2][4096];   // [buf][kc0..3][128][8]
    int tid = threadIdx.x;
    int lane = tid & 63;
    int wave = tid >> 6;
    int l31 = lane & 31, h5 = lane >> 5;
    int nwg = gridDim.x;
    int q = nwg >> 3, r = nwg & 7;
    int xcd = blockIdx.x & 7, idx = blockIdx.x >> 3;
    int wgid = (xcd < r ? xcd * (q + 1) : r * (q + 1) + (xcd - r) * q) + idx;
    int mt = wgid / nn_tiles;
    int nt = wgid - mt * nn_tiles;
    int m0 = mt * 64, n0 = nt * 128;
    int wm = (wave & 1) * 32, wn2 = (wave >> 1) * 64;

    int srA = tid & 63, skA = tid >> 6;
    int srW = tid & 127, skW = tid >> 7;
    int arow = m0 + srA; if (arow >= M) arow = M - 1;
    int wrow = n0 + srW; if (wrow >= N) wrow = N - 1;
    const _Float16* Ag = A + (size_t)arow * K + skA * 8;
    const _Float16* Wg = W + (size_t)wrow * K + skW * 8;
    _Float16* AsD = As[0] + (size_t)(tid & ~63) * 8;
    _Float16* WsD = Ws[0] + (size_t)(tid & ~63) * 8;

    floatx16 acc0, acc1;
#pragma unroll
    for (int i = 0; i < 16; ++i) { acc0[i] = 0.f; acc1[i] = 0.f; }

    gll16(Ag, AsD);
    gll16(Wg, WsD);
    gll16(Wg + 16, WsD + 2048);
    __syncthreads();

    int nk = K >> 5;
    for (int t = 0; t < nk; ++t) {
        int buf = t & 1;
        if (t + 1 < nk) {
            int k0 = (t + 1) * 32;
            int bo = buf ^ 1;
            gll16(Ag + k0, AsD + bo * 2048);
            gll16(Wg + k0, WsD + bo * 4096);
            gll16(Wg + k0 + 16, WsD + bo * 4096 + 2048);
        }
        const _Float16* Asb = As[buf];
        const _Float16* Wsb = Ws[buf];
#pragma unroll
        for (int ks = 0; ks < 2; ++ks) {
            int kc = ks * 2 + h5;
            f16x8 a  = *(const f16x8*)(Asb + kc * 512 + (wm + l31) * 8);
            f16x8 b0 = *(const f16x8*)(Wsb + kc * 1024 + (wn2 + l31) * 8);
            f16x8 b1 = *(const f16x8*)(Wsb + kc * 1024 + (wn2 + 32 + l31) * 8);
            acc0 = __builtin_amdgcn_mfma_f32_32x32x16_f16(a, b0, acc0, 0, 0, 0);
            acc1 = __builtin_amdgcn_mfma_f32_32x32x16_f16(a, b1, acc1, 0, 0, 0);
        }
        __syncthreads();
    }

#pragma unroll
    for (int nj = 0; nj < 2; ++nj) {
        int nn = n0 + wn2 + nj * 32 + l31;
        if (nn >= N) continue;
        const floatx16& ac = nj ? acc1 : acc0;
#pragma unroll
        for (int r2 = 0; r2 < 16; ++r2) {
            int mm = m0 + wm + (r2 & 3) + 8 * (r2 >> 2) + 4 * h5;
            if (mm >= M) continue;
            Ch[(size_t)mm * N + nn] = (_Float16)ac[r2];
        }
    }
}

// ======================= MFMA GEMM: 64x64 tile, BK=64 (4 MFMA/barrier) ==========
// MODE 1: X += acc (fp32)   MODE 2: X[(b*SL+sidx[m])*N+n] += acc*sprob[m]
template<int MODE>
__global__ __launch_bounds__(256) void gemm_mfma(const _Float16* __restrict__ A,
        const _Float16* __restrict__ W, _Float16* __restrict__ Ch, float* __restrict__ X,
        int M, int N, int K, int nn_tiles, const int* __restrict__ sidx, const float* __restrict__ sprob) {
    __shared__ __attribute__((aligned(16))) _Float16 As[2][4096];   // [buf][kc0..7][64][8]
    __shared__ __attribute__((aligned(16))) _Float16 Ws[2][4096];
    int tid = threadIdx.x;
    int lane = tid & 63;
    int wave = tid >> 6;
    int l31 = lane & 31, h5 = lane >> 5;
    int nwg = gridDim.x;
    int q = nwg >> 3, r = nwg & 7;
    int xcd = blockIdx.x & 7, idx = blockIdx.x >> 3;
    int wgid = (xcd < r ? xcd * (q + 1) : r * (q + 1) + (xcd - r) * q) + idx;
    int mt = wgid / nn_tiles;
    int nt = wgid - mt * nn_tiles;
    int m0 = mt * 64, n0 = nt * 64;
    int wm = (wave & 1) * 32, wn = (wave >> 1) * 32;

    int srow = tid & 63;
    int skc = tid >> 6;          // 0..3
    int arow = m0 + srow; if (arow >= M) arow = M - 1;
    int wrow = n0 + srow; if (wrow >= N) wrow = N - 1;
    const _Float16* Ag = A + (size_t)arow * K + skc * 8;
    const _Float16* Wg = W + (size_t)wrow * K + skc * 8;
    _Float16* AsD = As[0] + (size_t)(tid & ~63) * 8;
    _Float16* WsD = Ws[0] + (size_t)(tid & ~63) * 8;

    floatx16 acc;
#pragma unroll
    for (int i = 0; i < 16; ++i) acc[i] = 0.f;

    int nk32 = K >> 5;
    int nfull = nk32 >> 1;
    int tail = nk32 & 1;

    gll16(Ag, AsD);
    gll16(Wg, WsD);
    gll16(Ag + 32, AsD + 2048);
    gll16(Wg + 32, WsD + 2048);
    __syncthreads();

    for (int t = 0; t < nfull; ++t) {
        int buf = t & 1;
        int bo = (buf ^ 1) * 4096;
        if (t + 1 < nfull) {
            int k0 = (t + 1) * 64;
            gll16(Ag + k0, AsD + bo);
            gll16(Wg + k0, WsD + bo);
            gll16(Ag + k0 + 32, AsD + bo + 2048);
            gll16(Wg + k0 + 32, WsD + bo + 2048);
        } else if (tail) {
            int k0 = nfull * 64;
            gll16(Ag + k0, AsD + bo);
            gll16(Wg + k0, WsD + bo);
        }
        const _Float16* Asb = As[buf];
        const _Float16* Wsb = Ws[buf];
#pragma unroll
        for (int ks = 0; ks < 4; ++ks) {
            int kc = ks * 2 + h5;
            f16x8 a = *(const f16x8*)(Asb + kc * 512 + (wm + l31) * 8);
            f16x8 b = *(const f16x8*)(Wsb + kc * 512 + (wn + l31) * 8);
            acc = __builtin_amdgcn_mfma_f32_32x32x16_f16(a, b, acc, 0, 0, 0);
        }
        __syncthreads();
    }
    if (tail) {
        int buf = nfull & 1;
        const _Float16* Asb = As[buf];
        const _Float16* Wsb = Ws[buf];
#pragma unroll
        for (int ks = 0; ks < 2; ++ks) {
            int kc = ks * 2 + h5;
            f16x8 a = *(const f16x8*)(Asb + kc * 512 + (wm + l31) * 8);
            f16x8 b = *(const f16x8*)(Wsb + kc * 512 + (wn + l31) * 8);
            acc = __builtin_amdgcn_mfma_f32_32x32x16_f16(a, b, acc, 0, 0, 0);
        }
    }

    int nn = n0 + wn + l31;
#pragma unroll
    for (int r2 = 0; r2 < 16; ++r2) {
        int mm = m0 + wm + (r2 & 3) + 8 * (r2 >> 2) + 4 * h5;
        if (mm >= M || nn >= N) continue;
        float v = acc[r2];
        if (MODE == 1) {
            X[(size_t)mm * N + nn] += v;
        } else {
            int b = mm / KK;
            X[((size_t)(b * SL + sidx[mm])) * N + nn] += v * sprob[mm];
        }
    }
}

// ============ fused gate+up GEMM: 64x128 tile (8 MFMA + 5 staging per barrier) ========
__global__ __launch_bounds__(256) void gemm_gateup(const _Float16* __restrict__ A,
        const _Float16* __restrict__ Wg, const _Float16* __restrict__ Wu,
        _Float16* __restrict__ Ch, int M, int N, int K, int nn_tiles) {
    __shared__ __attribute__((aligned(16))) _Float16 As[2][2048];
    __shared__ __attribute__((aligned(16))) _Float16 Wgs[2][4096];
    __shared__ __attribute__((aligned(16))) _Float16 Wus[2][4096];
    int tid = threadIdx.x;
    int lane = tid & 63;
    int wave = tid >> 6;
    int l31 = lane & 31, h5 = lane >> 5;
    int nwg = gridDim.x;
    int q = nwg >> 3, r = nwg & 7;
    int xcd = blockIdx.x & 7, idx = blockIdx.x >> 3;
    int wgid = (xcd < r ? xcd * (q + 1) : r * (q + 1) + (xcd - r) * q) + idx;
    int mt = wgid / nn_tiles;
    int nt = wgid - mt * nn_tiles;
    int m0 = mt * 64, n0 = nt * 128;
    int wm = (wave & 1) * 32, wn2 = (wave >> 1) * 64;

    int srA = tid & 63, skA = tid >> 6;
    int srW = tid & 127, skW = tid >> 7;
    int arow = m0 + srA; if (arow >= M) arow = M - 1;
    int wrow = n0 + srW; if (wrow >= N) wrow = N - 1;
    const _Float16* Ag  = A  + (size_t)arow * K + skA * 8;
    const _Float16* Wgg = Wg + (size_t)wrow * K + skW * 8;
    const _Float16* Wug = Wu + (size_t)wrow * K + skW * 8;
    _Float16* AsD  = As[0]  + (size_t)(tid & ~63) * 8;
    _Float16* WgsD = Wgs[0] + (size_t)(tid & ~63) * 8;
    _Float16* WusD = Wus[0] + (size_t)(tid & ~63) * 8;

    floatx16 ag0, ag1, au0, au1;
#pragma unroll
    for (int i = 0; i < 16; ++i) { ag0[i] = 0.f; ag1[i] = 0.f; au0[i] = 0.f; au1[i] = 0.f; }

    gll16(Ag, AsD);
    gll16(Wgg, WgsD);
    gll16(Wgg + 16, WgsD + 2048);
    gll16(Wug, WusD);
    gll16(Wug + 16, WusD + 2048);
    __syncthreads();

    int nk = K >> 5;
    for (int t = 0; t < nk; ++t) {
        int buf = t & 1;
        if (t + 1 < nk) {
            int k0 = (t + 1) * 32;
            int bo = buf ^ 1;
            gll16(Ag + k0, AsD + bo * 2048);
            gll16(Wgg + k0, WgsD + bo * 4096);
            gll16(Wgg + k0 + 16, WgsD + bo * 4096 + 2048);
            gll16(Wug + k0, WusD + bo * 4096);
            gll16(Wug + k0 + 16, WusD + bo * 4096 + 2048);
        }
        const _Float16* Asb = As[buf];
        const _Float16* Wgb = Wgs[buf];
        const _Float16* Wub = Wus[buf];
#pragma unroll
        for (int ks = 0; ks < 2; ++ks) {
            int kc = ks * 2 + h5;
            f16x8 a  = *(const f16x8*)(Asb + kc * 512 + (wm + l31) * 8);
            f16x8 g0 = *(const f16x8*)(Wgb + kc * 1024 + (wn2 + l31) * 8);
            f16x8 g1 = *(const f16x8*)(Wgb + kc * 1024 + (wn2 + 32 + l31) * 8);
            f16x8 u0 = *(const f16x8*)(Wub + kc * 1024 + (wn2 + l31) * 8);
            f16x8 u1 = *(const f16x8*)(Wub + kc * 1024 + (wn2 + 32 + l31) * 8);
            ag0 = __builtin_amdgcn_mfma_f32_32x32x16_f16(a, g0, ag0, 0, 0, 0);
            au0 = __builtin_amdgcn_mfma_f32_32x32x16_f16(a, u0, au0, 0, 0, 0);
            ag1 = __builtin_amdgcn_mfma_f32_32x32x16_f16(a, g1, ag1, 0, 0, 0);
            au1 = __builtin_amdgcn_mfma_f32_32x32x16_f16(a, u1, au1, 0, 0, 0);
        }
        __syncthreads();
    }

#pragma unroll
    for (int nj = 0; nj < 2; ++nj) {
        int nn = n0 + wn2 + nj * 32 + l31;
        if (nn >= N) continue;
        const floatx16& gA = nj ? ag1 : ag0;
        const floatx16& uA = nj ? au1 : au0;
#pragma unroll
        for (int r2 = 0; r2 < 16; ++r2) {
            int mm = m0 + wm + (r2 & 3) + 8 * (r2 >> 2) + 4 * h5;
            if (mm >= M) continue;
            float gv = gA[r2], uv = uA[r2];
            Ch[(size_t)mm * N + nn] = (_Float16)((gv / (1.f + __expf(-gv))) * uv);
        }
    }
}

// ======================= launch =======================
extern "C" void kernel_launch(void* const* d_in, const int* in_sizes, int n_in,
                              void* d_out, int out_size, void* d_ws, size_t ws_size,
                              hipStream_t stream) {
    const int*   ids          = (const int*)d_in[0];
    const int*   iter         = (const int*)d_in[1];
    const float* emb          = (const float*)d_in[2];
    const float* iter_emb     = (const float*)d_in[3];
    const float* attn_norm_w  = (const float*)d_in[4];
    const float* Wqkv         = (const float*)d_in[5];
    const float* wo_w         = (const float*)d_in[6];
    const float* router_w     = (const float*)d_in[7];
    const float* mlp_norm_w   = (const float*)d_in[8];
    const float* gate_w       = (const float*)d_in[9];
    const float* up_w         = (const float*)d_in[10];
    const float* down_w       = (const float*)d_in[11];
    const float* final_norm_w = (const float*)d_in[12];
    float* out = (float*)d_out;

    const size_t XN   = (size_t)BB * SL * DD;        // 5,242,880
    const size_t QKVN = (size_t)BB * SL * 3 * DD;    // 15,728,640
    const size_t HN   = (size_t)BB * NH * SL * 64;   // 5,242,880
    char* ws = (char*)d_ws;
    size_t off = 0;
    float*    x        = (float*)(ws + off);    off += XN * 4;
    _Float16* h        = (_Float16*)(ws + off); off += XN * 2;
    _Float16* attn_out = (_Float16*)(ws + off); off += XN * 2;
    float*    probs    = (float*)(ws + off);    off += (size_t)BB * SL * 4;
    int*      tkidx    = (int*)(ws + off);      off += (size_t)BB * KK * 4;
    float*    tkprob   = (float*)(ws + off);    off += (size_t)BB * KK * 4;
    off = (off + 255) & ~(size_t)255;
    _Float16* qkvh     = (_Float16*)(ws + off); off += QKVN * 2;   // reused as g1
    _Float16* Qh       = (_Float16*)(ws + off); off += HN * 2;
    _Float16* Kh       = (_Float16*)(ws + off); off += HN * 2;
    _Float16* Vh       = (_Float16*)(ws + off); off += HN * 2;
    float2*   ropet    = (float2*)(ws + off);   off += (size_t)SL * 32 * 8;   // 512 KB
    _Float16* WqkvH    = (_Float16*)(ws + off);
    _Float16* woH   = WqkvH + (size_t)NL * 3 * DD * DD;
    _Float16* gateH = woH   + (size_t)NL * DD * DD;
    _Float16* upH   = gateH + (size_t)NL * FF * DD;
    _Float16* downH = upH   + (size_t)NL * FF * DD;
    _Float16* g1 = qkvh;

    rope_init_kernel<<<SL * 32 / 256, 256, 0, stream>>>(ropet);
    cast4_kernel<<<(NL * 3 * DD * DD / 4 + 255) / 256, 256, 0, stream>>>(Wqkv, WqkvH, NL * 3 * DD * DD / 4);
    cast4_kernel<<<(NL * DD * DD / 4 + 255) / 256, 256, 0, stream>>>(wo_w, woH, NL * DD * DD / 4);
    cast4_kernel<<<(NL * FF * DD / 4 + 255) / 256, 256, 0, stream>>>(gate_w, gateH, NL * FF * DD / 4);
    cast4_kernel<<<(NL * FF * DD / 4 + 255) / 256, 256, 0, stream>>>(up_w, upH, NL * FF * DD / 4);
    cast4_kernel<<<(NL * DD * FF / 4 + 255) / 256, 256, 0, stream>>>(down_w, downH, NL * DD * FF / 4);

    embed_kernel<<<20480, 256, 0, stream>>>(ids, iter, emb, iter_emb, x);

    const int M1 = BB * SL;    // 16384
    const int M2 = BB * KK;    // 13104
    const int MT1 = (M1 + 63) / 64;    // 256
    const int MT2 = (M2 + 63) / 64;    // 205
    for (int l = 0; l < NL; ++l) {
        rmsnorm_kernel<_Float16><<<4096, 256, 0, stream>>>(x, attn_norm_w + l * DD, h, M1);
        gemm_qkv<<<MT1 * 8, 256, 0, stream>>>(h, WqkvH + (size_t)l * 3 * DD * DD,
                                              qkvh, M1, 3 * DD, DD, 8);
        prep_kernel<<<dim3(SL / 64, NH, BB), 256, 0, stream>>>(qkvh, ropet, Qh, Kh, Vh);
        attn_mfma<<<BB * NH * (SL / 64) / 2, 256, 0, stream>>>(Qh, Kh, Vh, attn_out);
        gemm_mfma<1><<<MT1 * 5, 256, 0, stream>>>(attn_out, woH + (size_t)l * DD * DD,
                                                  nullptr, x, M1, DD, DD, 5, nullptr, nullptr);
        router_kernel<<<4096, 256, 0, stream>>>(x, router_w + l * DD, probs, M1);
        topk_kernel<<<BB, 1024, 0, stream>>>(probs, tkidx, tkprob);
        gather_rmsnorm_kernel<<<3276, 256, 0, stream>>>(x, tkidx, mlp_norm_w + l * DD, h, M2);
        gemm_gateup<<<MT2 * 7, 256, 0, stream>>>(h, gateH + (size_t)l * FF * DD,
                                                 upH + (size_t)l * FF * DD, g1, M2, FF, DD, 7);
        gemm_mfma<2><<<MT2 * 5, 256, 0, stream>>>(g1, downH + (size_t)l * DD * FF,
                                                  nullptr, x, M2, DD, FF, 5, tkidx, tkprob);
    }
    rmsnorm_kernel<float><<<4096, 256, 0, stream>>>(x, final_norm_w, out, M1);
}

// Round 11
// 1539.558 us; speedup vs baseline: 1.1200x; 1.1200x over previous
//
#include <hip/hip_runtime.h>
#include <hip/hip_bf16.h>
#include <math.h>

#define VSZ 1056
#define DD 320
#define NH 5
#define HD 64
#define FF 864
#define NL 6
#define NLOOPS 8
#define BB 8
#define SL 2048
#define KK 1638          // int(2048 * 0.8)
#define EPSF 1e-6f

typedef _Float16 f16x8 __attribute__((ext_vector_type(8)));
typedef _Float16 f16x4 __attribute__((ext_vector_type(4)));
typedef float floatx16 __attribute__((ext_vector_type(16)));

__device__ inline void gll16(const void* g, void* l) {
    __builtin_amdgcn_global_load_lds((const __attribute__((address_space(1))) void*)g,
                                     (__attribute__((address_space(3))) void*)l, 16, 0, 0);
}

// ======================= cast fp32 -> fp16 (x4) =======================
__global__ __launch_bounds__(256) void cast4_kernel(const float* __restrict__ s,
        _Float16* __restrict__ d, int n4) {
    int i = blockIdx.x * 256 + threadIdx.x;
    if (i >= n4) return;
    float4 v = ((const float4*)s)[i];
    f16x4 o = { (_Float16)v.x, (_Float16)v.y, (_Float16)v.z, (_Float16)v.w };
    *(f16x4*)(d + (size_t)i * 4) = o;
}

// ======================= RoPE table init (once): tab[s][j] = (cos, sin)(s * freq_j) ===
__global__ __launch_bounds__(256) void rope_init_kernel(float2* __restrict__ tab) {
    int i = blockIdx.x * 256 + threadIdx.x;          // over SL*32
    int s = i >> 5, j = i & 31;
    float freq = exp2f(-(float)j * 0.4152410118609203f);   // 10000^(-j/32)
    float ang = (float)s * freq;
    tab[i] = make_float2(cosf(ang), sinf(ang));
}

// ======================= embed =======================
__global__ __launch_bounds__(256) void embed_kernel(const int* __restrict__ ids,
        const int* __restrict__ iter, const float* __restrict__ emb,
        const float* __restrict__ iter_emb, float* __restrict__ x) {
    int i = blockIdx.x * 256 + threadIdx.x;          // over B*S*D
    int d = i % DD, bs = i / DD;
    float v = emb[(size_t)ids[bs] * DD + d];
    int it = iter[0];
    if (it < NLOOPS) v += iter_emb[it * DD + d];
    x[i] = v;
}

// ======================= rmsnorm (1 wave per row, D=320 -> 5/lane) =======================
template<typename OT>
__global__ __launch_bounds__(256) void rmsnorm_kernel(const float* __restrict__ x,
        const float* __restrict__ w, OT* __restrict__ out, int nrows) {
    int row = blockIdx.x * 4 + (threadIdx.x >> 6);
    int lane = threadIdx.x & 63;
    if (row >= nrows) return;
    const float* xr = x + (size_t)row * DD;
    float v[5]; float ss = 0.f;
#pragma unroll
    for (int i = 0; i < 5; ++i) { v[i] = xr[lane + i * 64]; ss += v[i] * v[i]; }
#pragma unroll
    for (int o = 32; o > 0; o >>= 1) ss += __shfl_xor(ss, o);
    float r = rsqrtf(ss * (1.f / DD) + EPSF);
    OT* orow = out + (size_t)row * DD;
#pragma unroll
    for (int i = 0; i < 5; ++i) orow[lane + i * 64] = (OT)(w[lane + i * 64] * v[i] * r);
}

// gather selected tokens + rmsnorm -> fp16
__global__ __launch_bounds__(256) void gather_rmsnorm_kernel(const float* __restrict__ x,
        const int* __restrict__ tkidx, const float* __restrict__ w,
        _Float16* __restrict__ out, int nrows) {
    int row = blockIdx.x * 4 + (threadIdx.x >> 6);
    int lane = threadIdx.x & 63;
    if (row >= nrows) return;
    int b = row / KK;
    int t = tkidx[row];
    const float* xr = x + ((size_t)b * SL + t) * DD;
    float v[5]; float ss = 0.f;
#pragma unroll
    for (int i = 0; i < 5; ++i) { v[i] = xr[lane + i * 64]; ss += v[i] * v[i]; }
#pragma unroll
    for (int o = 32; o > 0; o >>= 1) ss += __shfl_xor(ss, o);
    float r = rsqrtf(ss * (1.f / DD) + EPSF);
    _Float16* orow = out + (size_t)row * DD;
#pragma unroll
    for (int i = 0; i < 5; ++i) orow[lane + i * 64] = (_Float16)(w[lane + i * 64] * v[i] * r);
}

// ======================= router: sigmoid(x . rw) =======================
__global__ __launch_bounds__(256) void router_kernel(const float* __restrict__ x,
        const float* __restrict__ rw, float* __restrict__ probs, int nrows) {
    int row = blockIdx.x * 4 + (threadIdx.x >> 6);
    int lane = threadIdx.x & 63;
    if (row >= nrows) return;
    const float* xr = x + (size_t)row * DD;
    float ss = 0.f;
#pragma unroll
    for (int i = 0; i < 5; ++i) ss += xr[lane + i * 64] * rw[lane + i * 64];
#pragma unroll
    for (int o = 32; o > 0; o >>= 1) ss += __shfl_xor(ss, o);
    if (lane == 0) probs[row] = 1.f / (1.f + __expf(-ss));
}

// ======================= top-k: radix select on packed (probbits<<32 | 2047-i) ===========
__global__ __launch_bounds__(1024) void topk_kernel(const float* __restrict__ probs,
        int* __restrict__ tkidx, float* __restrict__ tkprob) {
    __shared__ int hist[256];
    __shared__ int scn[256];
    __shared__ int outc;
    __shared__ int s_digit, s_rem;
    int b = blockIdx.x, tid = threadIdx.x;
    unsigned long long k0, k1;
    {
        unsigned int f0 = __float_as_uint(probs[b * SL + tid]);
        unsigned int f1 = __float_as_uint(probs[b * SL + tid + 1024]);
        k0 = ((unsigned long long)f0 << 32) | (unsigned int)(2047 - tid);
        k1 = ((unsigned long long)f1 << 32) | (unsigned int)(2047 - (tid + 1024));
    }
    if (tid == 0) outc = 0;
    unsigned long long prefix = 0, pmask = 0;
    int target = KK;
    for (int shift = 56; shift >= 0; shift -= 8) {
        if (tid < 256) hist[tid] = 0;
        __syncthreads();
        bool a0 = (k0 & pmask) == prefix;
        bool a1 = (k1 & pmask) == prefix;
        int d0 = (int)((k0 >> shift) & 255);
        int d1 = (int)((k1 >> shift) & 255);
        if (a0) atomicAdd(&hist[d0], 1);
        if (a1) atomicAdd(&hist[d1], 1);
        __syncthreads();
        if (tid < 64) {                       // wave 0: suffix scan of 256 bins
            int h0 = hist[tid * 4], h1 = hist[tid * 4 + 1];
            int h2 = hist[tid * 4 + 2], h3 = hist[tid * 4 + 3];
            int s3 = h3, s2 = h2 + s3, s1 = h1 + s2, s0 = h0 + s1;
            int s = s0;
#pragma unroll
            for (int off = 1; off < 64; off <<= 1) {
                int v = __shfl_down(s, off);
                if (tid + off >= 64) v = 0;
                s += v;
            }
            int A = s - s0;                   // sum of later lanes' bins
            scn[tid * 4]     = s0 + A;
            scn[tid * 4 + 1] = s1 + A;
            scn[tid * 4 + 2] = s2 + A;
            scn[tid * 4 + 3] = s3 + A;
        }
        __syncthreads();
        if (tid < 256 && hist[tid] > 0) {
            int S = scn[tid];                 // count digit >= tid
            int Sgt = S - hist[tid];          // count digit >  tid
            if (Sgt < target && target <= S) { s_digit = tid; s_rem = target - Sgt; }
        }
        __syncthreads();
        int dsel = s_digit, rem = s_rem;
        bool full = (rem == hist[dsel]);
        if (a0 && (d0 > dsel || (full && d0 == dsel))) {
            int s = atomicAdd(&outc, 1);
            tkidx[b * KK + s] = 2047 - (int)(k0 & 0xffffffffu);
            tkprob[b * KK + s] = __uint_as_float((unsigned int)(k0 >> 32));
        }
        if (a1 && (d1 > dsel || (full && d1 == dsel))) {
            int s = atomicAdd(&outc, 1);
            tkidx[b * KK + s] = 2047 - (int)(k1 & 0xffffffffu);
            tkprob[b * KK + s] = __uint_as_float((unsigned int)(k1 >> 32));
        }
        if (full) break;
        target = rem;
        prefix |= ((unsigned long long)dsel) << shift;
        pmask  |= ((unsigned long long)255) << shift;
        __syncthreads();
    }
}

// ======================= prep: RoPE (table-based), Q scaled by log2e/8, K/V tiled ======
__global__ __launch_bounds__(256) void prep_kernel(const _Float16* __restrict__ qkv,
        const float2* __restrict__ ropet,
        _Float16* __restrict__ Qh, _Float16* __restrict__ Kt, _Float16* __restrict__ Vt) {
    __shared__ _Float16 vt[64][72];
    int tid = threadIdx.x;
    int t = blockIdx.x, h = blockIdx.y, b = blockIdx.z;
    int bh = b * NH + h;
    int c = tid >> 5;            // d-chunk 0..7
    int slb = tid & 31;
    const float QS = 0.125f * 1.44269504088896341f;   // 1/sqrt(HD) folded with log2(e)
#pragma unroll
    for (int half = 0; half < 2; ++half) {
        int sl = half * 32 + slb;
        int s = t * 64 + sl;
        size_t rbase = ((size_t)(b * SL + s) * 3) * (NH * 64) + h * 64;
        f16x8 qv = *(const f16x8*)(qkv + rbase + c * 8);
        f16x8 qp = *(const f16x8*)(qkv + rbase + (c ^ 4) * 8);
        f16x8 kv = *(const f16x8*)(qkv + rbase + NH * 64 + c * 8);
        f16x8 kp = *(const f16x8*)(qkv + rbase + NH * 64 + (c ^ 4) * 8);
        f16x8 vv = *(const f16x8*)(qkv + rbase + 2 * NH * 64 + c * 8);
        const float2* rp = ropet + (size_t)s * 32 + (c & 3) * 8;
        f16x8 qo, ko;
#pragma unroll
        for (int j = 0; j < 8; ++j) {
            int d = c * 8 + j;
            float2 cs = rp[j];
            float cc = cs.x, sn = cs.y;
            float a = (float)qv[j], p = (float)qp[j];
            float ka = (float)kv[j], kb2 = (float)kp[j];
            float qr = (d < 32) ? a * cc - p * sn : a * cc + p * sn;
            float kr = (d < 32) ? ka * cc - kb2 * sn : ka * cc + kb2 * sn;
            qo[j] = (_Float16)(qr * QS);
            ko[j] = (_Float16)kr;
        }
        *(f16x8*)(Qh + ((size_t)bh * SL + s) * 64 + c * 8) = qo;
        *(f16x8*)(Kt + (((size_t)bh * 32 + t) * 8 + c) * 512 + sl * 8) = ko;
        *(f16x8*)(&vt[sl][c * 8]) = vv;
    }
    __syncthreads();
#pragma unroll
    for (int gg = 0; gg < 2; ++gg) {
        int oo = tid * 16 + gg * 8;
        int kc = oo >> 9;            // storage kc8: 0..7
        int d = (oo >> 3) & 63;
        f16x8 vo;
#pragma unroll
        for (int j = 0; j < 8; ++j) {
            int key = (kc >> 1) * 16 + (j & 3) + 8 * (j >> 2) + 4 * (kc & 1);
            vo[j] = vt[key][d];
        }
        *(f16x8*)(Vt + (((size_t)bh * 32 + t) * 8 + kc) * 512 + d * 8) = vo;
    }
}

// ======= attention (R5 version): per-block 32 queries, 4 waves split key-tiles,
// operands direct from L2 in fragment layout, exp2 softmax with defer-max,
// zero-shuffle P->B operand (V key-permuted in prep), two-round combine.
__global__ __launch_bounds__(256, 2) void attn_mfma(const _Float16* __restrict__ Qh,
        const _Float16* __restrict__ Kt, const _Float16* __restrict__ Vt,
        _Float16* __restrict__ attn_out) {
    __shared__ float red[4][32][32];
    __shared__ float msh[4][32];
    __shared__ float lsh[4][32];
    int tid = threadIdx.x;
    int w = tid >> 6;
    int lane = tid & 63;
    int l31 = lane & 31, h5 = lane >> 5;
    int g = blockIdx.x;
    int j = g >> 3;
    int bh = (g & 7) + 8 * (j >> 6);     // 0..39
    int qt = 63 - (j & 63);              // longest blocks first
    int b = bh / NH, h = bh % NH;
    int nt = (qt >> 1) + 1;
    int qw = qt * 32;
    int myq = qw + l31;

    f16x8 qf[4];
    const _Float16* qrow = Qh + ((size_t)bh * SL + myq) * 64;
#pragma unroll
    for (int kd = 0; kd < 4; ++kd) qf[kd] = *(const f16x8*)(qrow + kd * 16 + h5 * 8);

    const _Float16* Kb = Kt + (size_t)bh * 32 * 4096;
    const _Float16* Vb = Vt + (size_t)bh * 32 * 4096;

    floatx16 O0, O1;
#pragma unroll
    for (int r = 0; r < 16; ++r) { O0[r] = 0.f; O1[r] = 0.f; }
    float m = -INFINITY, l = 0.f;

    for (int t = w; t < nt; t += 4) {
        const _Float16* kb = Kb + (size_t)t * 4096;
        const _Float16* vb = Vb + (size_t)t * 4096;
        f16x8 a0[4], a1[4], v0[4], v1[4];
#pragma unroll
        for (int kd = 0; kd < 4; ++kd) {
            int off = (kd * 2 + h5) * 512 + l31 * 8;
            a0[kd] = *(const f16x8*)(kb + off);
            a1[kd] = *(const f16x8*)(kb + off + 256);
        }
#pragma unroll
        for (int kc = 0; kc < 4; ++kc) {
            int off = (kc * 2 + h5) * 512 + l31 * 8;
            v0[kc] = *(const f16x8*)(vb + off);
            v1[kc] = *(const f16x8*)(vb + off + 256);
        }
        floatx16 S0, S1;
#pragma unroll
        for (int r = 0; r < 16; ++r) { S0[r] = 0.f; S1[r] = 0.f; }
#pragma unroll
        for (int kd = 0; kd < 4; ++kd) {
            S0 = __builtin_amdgcn_mfma_f32_32x32x16_f16(a0[kd], qf[kd], S0, 0, 0, 0);
            S1 = __builtin_amdgcn_mfma_f32_32x32x16_f16(a1[kd], qf[kd], S1, 0, 0, 0);
        }
        int t0 = t * 64;
        if (t0 + 63 > qw) {                  // diagonal tile: causal mask
#pragma unroll
            for (int r = 0; r < 16; ++r) {
                int key = t0 + (r & 3) + 8 * (r >> 2) + 4 * h5;
                if (key > myq) S0[r] = -INFINITY;
                if (key + 32 > myq) S1[r] = -INFINITY;
            }
        }
        float tmax = S0[0];
#pragma unroll
        for (int r = 1; r < 16; ++r) tmax = fmaxf(tmax, S0[r]);
#pragma unroll
        for (int r = 0; r < 16; ++r) tmax = fmaxf(tmax, S1[r]);
        tmax = fmaxf(tmax, __shfl_xor(tmax, 32));
        if (__any(tmax > m + 8.f)) {         // defer-max (T13)
            float mnew = fmaxf(m, tmax);
            float alpha = exp2f(m - mnew);
            l *= alpha; O0 *= alpha; O1 *= alpha; m = mnew;
        }
        float P0[16], P1[16]; float psum = 0.f;
#pragma unroll
        for (int r = 0; r < 16; ++r) { P0[r] = exp2f(S0[r] - m); psum += P0[r]; }
#pragma unroll
        for (int r = 0; r < 16; ++r) { P1[r] = exp2f(S1[r] - m); psum += P1[r]; }
        psum += __shfl_xor(psum, 32);
        l += psum;
        // PV: straight register-run P (V key-permuted to match). 16 cvt_pkrtz, 0 shuffles.
#pragma unroll
        for (int sub = 0; sub < 2; ++sub) {
            const float* P = sub ? P1 : P0;
#pragma unroll
            for (int kc = 0; kc < 2; ++kc) {
                auto q01 = __builtin_amdgcn_cvt_pkrtz(P[kc * 8 + 0], P[kc * 8 + 1]);
                auto q23 = __builtin_amdgcn_cvt_pkrtz(P[kc * 8 + 2], P[kc * 8 + 3]);
                auto q45 = __builtin_amdgcn_cvt_pkrtz(P[kc * 8 + 4], P[kc * 8 + 5]);
                auto q67 = __builtin_amdgcn_cvt_pkrtz(P[kc * 8 + 6], P[kc * 8 + 7]);
                f16x8 pf;
                pf[0] = (_Float16)q01[0]; pf[1] = (_Float16)q01[1];
                pf[2] = (_Float16)q23[0]; pf[3] = (_Float16)q23[1];
                pf[4] = (_Float16)q45[0]; pf[5] = (_Float16)q45[1];
                pf[6] = (_Float16)q67[0]; pf[7] = (_Float16)q67[1];
                int ksg = sub * 2 + kc;
                O0 = __builtin_amdgcn_mfma_f32_32x32x16_f16(v0[ksg], pf, O0, 0, 0, 0);
                O1 = __builtin_amdgcn_mfma_f32_32x32x16_f16(v1[ksg], pf, O1, 0, 0, 0);
            }
        }
    }
    // -------- cross-wave combine (two rounds over d-halves) --------
    if (h5 == 0) msh[w][l31] = m;
    __syncthreads();
    float M = fmaxf(fmaxf(msh[0][l31], msh[1][l31]), fmaxf(msh[2][l31], msh[3][l31]));
    float wgt = exp2f(m - M);                // m=-inf (idle wave) -> 0
    if (h5 == 0) lsh[w][l31] = l * wgt;
#pragma unroll
    for (int r = 0; r < 16; ++r) {
        int d = (r & 3) + 8 * (r >> 2) + 4 * h5;
        red[w][d][l31] = O0[r] * wgt;
    }
    __syncthreads();
    float lsum = lsh[0][l31] + lsh[1][l31] + lsh[2][l31] + lsh[3][l31];
    float linv = 1.f / lsum;
    if (w < 2) {
        f16x8 ov;
#pragma unroll
        for (int k = 0; k < 8; ++k) {
            int d = w * 16 + h5 * 8 + k;
            ov[k] = (_Float16)((red[0][d][l31] + red[1][d][l31] +
                                red[2][d][l31] + red[3][d][l31]) * linv);
        }
        *(f16x8*)(attn_out + ((size_t)(b * SL + myq)) * DD + h * 64 + w * 16 + h5 * 8) = ov;
    }
    __syncthreads();
#pragma unroll
    for (int r = 0; r < 16; ++r) {
        int d = (r & 3) + 8 * (r >> 2) + 4 * h5;
        red[w][d][l31] = O1[r] * wgt;
    }
    __syncthreads();
    if (w >= 2) {
        f16x8 ov;
#pragma unroll
        for (int k = 0; k < 8; ++k) {
            int d = (w - 2) * 16 + h5 * 8 + k;
            ov[k] = (_Float16)((red[0][d][l31] + red[1][d][l31] +
                                red[2][d][l31] + red[3][d][l31]) * linv);
        }
        *(f16x8*)(attn_out + ((size_t)(b * SL + myq)) * DD + h * 64 + 32 + (w - 2) * 16 + h5 * 8) = ov;
    }
}

// =========== qkv GEMM: 64x128 tile (4 MFMA + 3 staging calls per barrier) ===========
__global__ __launch_bounds__(256) void gemm_qkv(const _Float16* __restrict__ A,
        const _Float16* __restrict__ W, _Float16* __restrict__ Ch,
        int M, int N, int K, int nn_tiles) {
    __shared__ __attribute__((aligned(16))) _Float16 As[2][2048];   // [buf][kc0..3][64][8]
    __shared__ __attribute__((aligned(16))) _Float16 Ws[2][4096];   // [buf][kc0..3][128][8]
    int tid = threadIdx.x;
    int lane = tid & 63;
    int wave = tid >> 6;
    int l31 = lane & 31, h5 = lane >> 5;
    int nwg = gridDim.x;
    int q = nwg >> 3, r = nwg & 7;
    int xcd = blockIdx.x & 7, idx = blockIdx.x >> 3;
    int wgid = (xcd < r ? xcd * (q + 1) : r * (q + 1) + (xcd - r) * q) + idx;
    int mt = wgid / nn_tiles;
    int nt = wgid - mt * nn_tiles;
    int m0 = mt * 64, n0 = nt * 128;
    int wm = (wave & 1) * 32, wn2 = (wave >> 1) * 64;

    int srA = tid & 63, skA = tid >> 6;
    int srW = tid & 127, skW = tid >> 7;
    int arow = m0 + srA; if (arow >= M) arow = M - 1;
    int wrow = n0 + srW; if (wrow >= N) wrow = N - 1;
    const _Float16* Ag = A + (size_t)arow * K + skA * 8;
    const _Float16* Wg = W + (size_t)wrow * K + skW * 8;
    _Float16* AsD = As[0] + (size_t)(tid & ~63) * 8;
    _Float16* WsD = Ws[0] + (size_t)(tid & ~63) * 8;

    floatx16 acc0, acc1;
#pragma unroll
    for (int i = 0; i < 16; ++i) { acc0[i] = 0.f; acc1[i] = 0.f; }

    gll16(Ag, AsD);
    gll16(Wg, WsD);
    gll16(Wg + 16, WsD + 2048);
    __syncthreads();

    int nk = K >> 5;
    for (int t = 0; t < nk; ++t) {
        int buf = t & 1;
        if (t + 1 < nk) {
            int k0 = (t + 1) * 32;
            int bo = buf ^ 1;
            gll16(Ag + k0, AsD + bo * 2048);
            gll16(Wg + k0, WsD + bo * 4096);
            gll16(Wg + k0 + 16, WsD + bo * 4096 + 2048);
        }
        const _Float16* Asb = As[buf];
        const _Float16* Wsb = Ws[buf];
#pragma unroll
        for (int ks = 0; ks < 2; ++ks) {
            int kc = ks * 2 + h5;
            f16x8 a  = *(const f16x8*)(Asb + kc * 512 + (wm + l31) * 8);
            f16x8 b0 = *(const f16x8*)(Wsb + kc * 1024 + (wn2 + l31) * 8);
            f16x8 b1 = *(const f16x8*)(Wsb + kc * 1024 + (wn2 + 32 + l31) * 8);
            acc0 = __builtin_amdgcn_mfma_f32_32x32x16_f16(a, b0, acc0, 0, 0, 0);
            acc1 = __builtin_amdgcn_mfma_f32_32x32x16_f16(a, b1, acc1, 0, 0, 0);
        }
        __syncthreads();
    }

#pragma unroll
    for (int nj = 0; nj < 2; ++nj) {
        int nn = n0 + wn2 + nj * 32 + l31;
        if (nn >= N) continue;
        const floatx16& ac = nj ? acc1 : acc0;
#pragma unroll
        for (int r2 = 0; r2 < 16; ++r2) {
            int mm = m0 + wm + (r2 & 3) + 8 * (r2 >> 2) + 4 * h5;
            if (mm >= M) continue;
            Ch[(size_t)mm * N + nn] = (_Float16)ac[r2];
        }
    }
}

// ======================= MFMA GEMM: 64x64 tile, BK=64 (4 MFMA/barrier) ==========
// MODE 1: X += acc (fp32)   MODE 2: X[(b*SL+sidx[m])*N+n] += acc*sprob[m]
template<int MODE>
__global__ __launch_bounds__(256) void gemm_mfma(const _Float16* __restrict__ A,
        const _Float16* __restrict__ W, _Float16* __restrict__ Ch, float* __restrict__ X,
        int M, int N, int K, int nn_tiles, const int* __restrict__ sidx, const float* __restrict__ sprob) {
    __shared__ __attribute__((aligned(16))) _Float16 As[2][4096];   // [buf][kc0..7][64][8]
    __shared__ __attribute__((aligned(16))) _Float16 Ws[2][4096];
    int tid = threadIdx.x;
    int lane = tid & 63;
    int wave = tid >> 6;
    int l31 = lane & 31, h5 = lane >> 5;
    int nwg = gridDim.x;
    int q = nwg >> 3, r = nwg & 7;
    int xcd = blockIdx.x & 7, idx = blockIdx.x >> 3;
    int wgid = (xcd < r ? xcd * (q + 1) : r * (q + 1) + (xcd - r) * q) + idx;
    int mt = wgid / nn_tiles;
    int nt = wgid - mt * nn_tiles;
    int m0 = mt * 64, n0 = nt * 64;
    int wm = (wave & 1) * 32, wn = (wave >> 1) * 32;

    int srow = tid & 63;
    int skc = tid >> 6;          // 0..3
    int arow = m0 + srow; if (arow >= M) arow = M - 1;
    int wrow = n0 + srow; if (wrow >= N) wrow = N - 1;
    const _Float16* Ag = A + (size_t)arow * K + skc * 8;
    const _Float16* Wg = W + (size_t)wrow * K + skc * 8;
    _Float16* AsD = As[0] + (size_t)(tid & ~63) * 8;
    _Float16* WsD = Ws[0] + (size_t)(tid & ~63) * 8;

    floatx16 acc;
#pragma unroll
    for (int i = 0; i < 16; ++i) acc[i] = 0.f;

    int nk32 = K >> 5;
    int nfull = nk32 >> 1;
    int tail = nk32 & 1;

    gll16(Ag, AsD);
    gll16(Wg, WsD);
    gll16(Ag + 32, AsD + 2048);
    gll16(Wg + 32, WsD + 2048);
    __syncthreads();

    for (int t = 0; t < nfull; ++t) {
        int buf = t & 1;
        int bo = (buf ^ 1) * 4096;
        if (t + 1 < nfull) {
            int k0 = (t + 1) * 64;
            gll16(Ag + k0, AsD + bo);
            gll16(Wg + k0, WsD + bo);
            gll16(Ag + k0 + 32, AsD + bo + 2048);
            gll16(Wg + k0 + 32, WsD + bo + 2048);
        } else if (tail) {
            int k0 = nfull * 64;
            gll16(Ag + k0, AsD + bo);
            gll16(Wg + k0, WsD + bo);
        }
        const _Float16* Asb = As[buf];
        const _Float16* Wsb = Ws[buf];
#pragma unroll
        for (int ks = 0; ks < 4; ++ks) {
            int kc = ks * 2 + h5;
            f16x8 a = *(const f16x8*)(Asb + kc * 512 + (wm + l31) * 8);
            f16x8 b = *(const f16x8*)(Wsb + kc * 512 + (wn + l31) * 8);
            acc = __builtin_amdgcn_mfma_f32_32x32x16_f16(a, b, acc, 0, 0, 0);
        }
        __syncthreads();
    }
    if (tail) {
        int buf = nfull & 1;
        const _Float16* Asb = As[buf];
        const _Float16* Wsb = Ws[buf];
#pragma unroll
        for (int ks = 0; ks < 2; ++ks) {
            int kc = ks * 2 + h5;
            f16x8 a = *(const f16x8*)(Asb + kc * 512 + (wm + l31) * 8);
            f16x8 b = *(const f16x8*)(Wsb + kc * 512 + (wn + l31) * 8);
            acc = __builtin_amdgcn_mfma_f32_32x32x16_f16(a, b, acc, 0, 0, 0);
        }
    }

    int nn = n0 + wn + l31;
#pragma unroll
    for (int r2 = 0; r2 < 16; ++r2) {
        int mm = m0 + wm + (r2 & 3) + 8 * (r2 >> 2) + 4 * h5;
        if (mm >= M || nn >= N) continue;
        float v = acc[r2];
        if (MODE == 1) {
            X[(size_t)mm * N + nn] += v;
        } else {
            int b = mm / KK;
            X[((size_t)(b * SL + sidx[mm])) * N + nn] += v * sprob[mm];
        }
    }
}

// ============ fused gate+up GEMM: 64x128 tile (8 MFMA + 5 staging per barrier) ========
__global__ __launch_bounds__(256) void gemm_gateup(const _Float16* __restrict__ A,
        const _Float16* __restrict__ Wg, const _Float16* __restrict__ Wu,
        _Float16* __restrict__ Ch, int M, int N, int K, int nn_tiles) {
    __shared__ __attribute__((aligned(16))) _Float16 As[2][2048];
    __shared__ __attribute__((aligned(16))) _Float16 Wgs[2][4096];
    __shared__ __attribute__((aligned(16))) _Float16 Wus[2][4096];
    int tid = threadIdx.x;
    int lane = tid & 63;
    int wave = tid >> 6;
    int l31 = lane & 31, h5 = lane >> 5;
    int nwg = gridDim.x;
    int q = nwg >> 3, r = nwg & 7;
    int xcd = blockIdx.x & 7, idx = blockIdx.x >> 3;
    int wgid = (xcd < r ? xcd * (q + 1) : r * (q + 1) + (xcd - r) * q) + idx;
    int mt = wgid / nn_tiles;
    int nt = wgid - mt * nn_tiles;
    int m0 = mt * 64, n0 = nt * 128;
    int wm = (wave & 1) * 32, wn2 = (wave >> 1) * 64;

    int srA = tid & 63, skA = tid >> 6;
    int srW = tid & 127, skW = tid >> 7;
    int arow = m0 + srA; if (arow >= M) arow = M - 1;
    int wrow = n0 + srW; if (wrow >= N) wrow = N - 1;
    const _Float16* Ag  = A  + (size_t)arow * K + skA * 8;
    const _Float16* Wgg = Wg + (size_t)wrow * K + skW * 8;
    const _Float16* Wug = Wu + (size_t)wrow * K + skW * 8;
    _Float16* AsD  = As[0]  + (size_t)(tid & ~63) * 8;
    _Float16* WgsD = Wgs[0] + (size_t)(tid & ~63) * 8;
    _Float16* WusD = Wus[0] + (size_t)(tid & ~63) * 8;

    floatx16 ag0, ag1, au0, au1;
#pragma unroll
    for (int i = 0; i < 16; ++i) { ag0[i] = 0.f; ag1[i] = 0.f; au0[i] = 0.f; au1[i] = 0.f; }

    gll16(Ag, AsD);
    gll16(Wgg, WgsD);
    gll16(Wgg + 16, WgsD + 2048);
    gll16(Wug, WusD);
    gll16(Wug + 16, WusD + 2048);
    __syncthreads();

    int nk = K >> 5;
    for (int t = 0; t < nk; ++t) {
        int buf = t & 1;
        if (t + 1 < nk) {
            int k0 = (t + 1) * 32;
            int bo = buf ^ 1;
            gll16(Ag + k0, AsD + bo * 2048);
            gll16(Wgg + k0, WgsD + bo * 4096);
            gll16(Wgg + k0 + 16, WgsD + bo * 4096 + 2048);
            gll16(Wug + k0, WusD + bo * 4096);
            gll16(Wug + k0 + 16, WusD + bo * 4096 + 2048);
        }
        const _Float16* Asb = As[buf];
        const _Float16* Wgb = Wgs[buf];
        const _Float16* Wub = Wus[buf];
#pragma unroll
        for (int ks = 0; ks < 2; ++ks) {
            int kc = ks * 2 + h5;
            f16x8 a  = *(const f16x8*)(Asb + kc * 512 + (wm + l31) * 8);
            f16x8 g0 = *(const f16x8*)(Wgb + kc * 1024 + (wn2 + l31) * 8);
            f16x8 g1 = *(const f16x8*)(Wgb + kc * 1024 + (wn2 + 32 + l31) * 8);
            f16x8 u0 = *(const f16x8*)(Wub + kc * 1024 + (wn2 + l31) * 8);
            f16x8 u1 = *(const f16x8*)(Wub + kc * 1024 + (wn2 + 32 + l31) * 8);
            ag0 = __builtin_amdgcn_mfma_f32_32x32x16_f16(a, g0, ag0, 0, 0, 0);
            au0 = __builtin_amdgcn_mfma_f32_32x32x16_f16(a, u0, au0, 0, 0, 0);
            ag1 = __builtin_amdgcn_mfma_f32_32x32x16_f16(a, g1, ag1, 0, 0, 0);
            au1 = __builtin_amdgcn_mfma_f32_32x32x16_f16(a, u1, au1, 0, 0, 0);
        }
        __syncthreads();
    }

#pragma unroll
    for (int nj = 0; nj < 2; ++nj) {
        int nn = n0 + wn2 + nj * 32 + l31;
        if (nn >= N) continue;
        const floatx16& gA = nj ? ag1 : ag0;
        const floatx16& uA = nj ? au1 : au0;
#pragma unroll
        for (int r2 = 0; r2 < 16; ++r2) {
            int mm = m0 + wm + (r2 & 3) + 8 * (r2 >> 2) + 4 * h5;
            if (mm >= M) continue;
            float gv = gA[r2], uv = uA[r2];
            Ch[(size_t)mm * N + nn] = (_Float16)((gv / (1.f + __expf(-gv))) * uv);
        }
    }
}

// ======================= launch =======================
extern "C" void kernel_launch(void* const* d_in, const int* in_sizes, int n_in,
                              void* d_out, int out_size, void* d_ws, size_t ws_size,
                              hipStream_t stream) {
    const int*   ids          = (const int*)d_in[0];
    const int*   iter         = (const int*)d_in[1];
    const float* emb          = (const float*)d_in[2];
    const float* iter_emb     = (const float*)d_in[3];
    const float* attn_norm_w  = (const float*)d_in[4];
    const float* Wqkv         = (const float*)d_in[5];
    const float* wo_w         = (const float*)d_in[6];
    const float* router_w     = (const float*)d_in[7];
    const float* mlp_norm_w   = (const float*)d_in[8];
    const float* gate_w       = (const float*)d_in[9];
    const float* up_w         = (const float*)d_in[10];
    const float* down_w       = (const float*)d_in[11];
    const float* final_norm_w = (const float*)d_in[12];
    float* out = (float*)d_out;

    const size_t XN   = (size_t)BB * SL * DD;        // 5,242,880
    const size_t QKVN = (size_t)BB * SL * 3 * DD;    // 15,728,640
    const size_t HN   = (size_t)BB * NH * SL * 64;   // 5,242,880
    char* ws = (char*)d_ws;
    size_t off = 0;
    float*    x        = (float*)(ws + off);    off += XN * 4;
    _Float16* h        = (_Float16*)(ws + off); off += XN * 2;
    _Float16* attn_out = (_Float16*)(ws + off); off += XN * 2;
    float*    probs    = (float*)(ws + off);    off += (size_t)BB * SL * 4;
    int*      tkidx    = (int*)(ws + off);      off += (size_t)BB * KK * 4;
    float*    tkprob   = (float*)(ws + off);    off += (size_t)BB * KK * 4;
    off = (off + 255) & ~(size_t)255;
    _Float16* qkvh     = (_Float16*)(ws + off); off += QKVN * 2;   // reused as g1
    _Float16* Qh       = (_Float16*)(ws + off); off += HN * 2;
    _Float16* Kh       = (_Float16*)(ws + off); off += HN * 2;
    _Float16* Vh       = (_Float16*)(ws + off); off += HN * 2;
    float2*   ropet    = (float2*)(ws + off);   off += (size_t)SL * 32 * 8;   // 512 KB
    _Float16* WqkvH    = (_Float16*)(ws + off);
    _Float16* woH   = WqkvH + (size_t)NL * 3 * DD * DD;
    _Float16* gateH = woH   + (size_t)NL * DD * DD;
    _Float16* upH   = gateH + (size_t)NL * FF * DD;
    _Float16* downH = upH   + (size_t)NL * FF * DD;
    _Float16* g1 = qkvh;

    rope_init_kernel<<<SL * 32 / 256, 256, 0, stream>>>(ropet);
    cast4_kernel<<<(NL * 3 * DD * DD / 4 + 255) / 256, 256, 0, stream>>>(Wqkv, WqkvH, NL * 3 * DD * DD / 4);
    cast4_kernel<<<(NL * DD * DD / 4 + 255) / 256, 256, 0, stream>>>(wo_w, woH, NL * DD * DD / 4);
    cast4_kernel<<<(NL * FF * DD / 4 + 255) / 256, 256, 0, stream>>>(gate_w, gateH, NL * FF * DD / 4);
    cast4_kernel<<<(NL * FF * DD / 4 + 255) / 256, 256, 0, stream>>>(up_w, upH, NL * FF * DD / 4);
    cast4_kernel<<<(NL * DD * FF / 4 + 255) / 256, 256, 0, stream>>>(down_w, downH, NL * DD * FF / 4);

    embed_kernel<<<20480, 256, 0, stream>>>(ids, iter, emb, iter_emb, x);

    const int M1 = BB * SL;    // 16384
    const int M2 = BB * KK;    // 13104
    const int MT1 = (M1 + 63) / 64;    // 256
    const int MT2 = (M2 + 63) / 64;    // 205
    for (int l = 0; l < NL; ++l) {
        rmsnorm_kernel<_Float16><<<4096, 256, 0, stream>>>(x, attn_norm_w + l * DD, h, M1);
        gemm_qkv<<<MT1 * 8, 256, 0, stream>>>(h, WqkvH + (size_t)l * 3 * DD * DD,
                                              qkvh, M1, 3 * DD, DD, 8);
        prep_kernel<<<dim3(SL / 64, NH, BB), 256, 0, stream>>>(qkvh, ropet, Qh, Kh, Vh);
        attn_mfma<<<BB * NH * (SL / 32), 256, 0, stream>>>(Qh, Kh, Vh, attn_out);
        gemm_mfma<1><<<MT1 * 5, 256, 0, stream>>>(attn_out, woH + (size_t)l * DD * DD,
                                                  nullptr, x, M1, DD, DD, 5, nullptr, nullptr);
        router_kernel<<<4096, 256, 0, stream>>>(x, router_w + l * DD, probs, M1);
        topk_kernel<<<BB, 1024, 0, stream>>>(probs, tkidx, tkprob);
        gather_rmsnorm_kernel<<<3276, 256, 0, stream>>>(x, tkidx, mlp_norm_w + l * DD, h, M2);
        gemm_gateup<<<MT2 * 7, 256, 0, stream>>>(h, gateH + (size_t)l * FF * DD,
                                                 upH + (size_t)l * FF * DD, g1, M2, FF, DD, 7);
        gemm_mfma<2><<<MT2 * 5, 256, 0, stream>>>(g1, downH + (size_t)l * DD * FF,
                                                  nullptr, x, M2, DD, FF, 5, tkidx, tkprob);
    }
    rmsnorm_kernel<float><<<4096, 256, 0, stream>>>(x, final_norm_w, out, M1);
}

// Round 12
// 1477.161 us; speedup vs baseline: 1.1673x; 1.0422x over previous
//
#include <hip/hip_runtime.h>
#include <hip/hip_bf16.h>
#include <math.h>

#define VSZ 1056
#define DD 320
#define NH 5
#define HD 64
#define FF 864
#define NL 6
#define NLOOPS 8
#define BB 8
#define SL 2048
#define KK 1638          // int(2048 * 0.8)
#define EPSF 1e-6f

typedef _Float16 f16x8 __attribute__((ext_vector_type(8)));
typedef _Float16 f16x4 __attribute__((ext_vector_type(4)));
typedef float floatx16 __attribute__((ext_vector_type(16)));

__device__ inline void gll16(const void* g, void* l) {
    __builtin_amdgcn_global_load_lds((const __attribute__((address_space(1))) void*)g,
                                     (__attribute__((address_space(3))) void*)l, 16, 0, 0);
}

// ======================= fused cast fp32 -> fp16 for all 5 weight tensors =============
__global__ __launch_bounds__(256) void cast5_kernel(
        const float* __restrict__ s1, const float* __restrict__ s2,
        const float* __restrict__ s3, const float* __restrict__ s4,
        const float* __restrict__ s5,
        _Float16* __restrict__ d1, _Float16* __restrict__ d2,
        _Float16* __restrict__ d3, _Float16* __restrict__ d4,
        _Float16* __restrict__ d5,
        int n1, int n2, int n3, int n4, int n5) {
    int i = blockIdx.x * 256 + threadIdx.x;
    const float* s; _Float16* d; int l = i;
    if (l < n1) { s = s1; d = d1; }
    else { l -= n1; if (l < n2) { s = s2; d = d2; }
    else { l -= n2; if (l < n3) { s = s3; d = d3; }
    else { l -= n3; if (l < n4) { s = s4; d = d4; }
    else { l -= n4; if (l >= n5) return; s = s5; d = d5; } } } }
    float4 v = ((const float4*)s)[l];
    f16x4 o = { (_Float16)v.x, (_Float16)v.y, (_Float16)v.z, (_Float16)v.w };
    *(f16x4*)(d + (size_t)l * 4) = o;
}

// ======================= RoPE table init (once): tab[s][j] = (cos, sin)(s * freq_j) ===
__global__ __launch_bounds__(256) void rope_init_kernel(float2* __restrict__ tab) {
    int i = blockIdx.x * 256 + threadIdx.x;          // over SL*32
    int s = i >> 5, j = i & 31;
    float freq = exp2f(-(float)j * 0.4152410118609203f);   // 10000^(-j/32)
    float ang = (float)s * freq;
    tab[i] = make_float2(cosf(ang), sinf(ang));
}

// ======================= embed =======================
__global__ __launch_bounds__(256) void embed_kernel(const int* __restrict__ ids,
        const int* __restrict__ iter, const float* __restrict__ emb,
        const float* __restrict__ iter_emb, float* __restrict__ x) {
    int i = blockIdx.x * 256 + threadIdx.x;          // over B*S*D
    int d = i % DD, bs = i / DD;
    float v = emb[(size_t)ids[bs] * DD + d];
    int it = iter[0];
    if (it < NLOOPS) v += iter_emb[it * DD + d];
    x[i] = v;
}

// ======================= rmsnorm (1 wave per row, D=320 -> 5/lane) =======================
template<typename OT>
__global__ __launch_bounds__(256) void rmsnorm_kernel(const float* __restrict__ x,
        const float* __restrict__ w, OT* __restrict__ out, int nrows) {
    int row = blockIdx.x * 4 + (threadIdx.x >> 6);
    int lane = threadIdx.x & 63;
    if (row >= nrows) return;
    const float* xr = x + (size_t)row * DD;
    float v[5]; float ss = 0.f;
#pragma unroll
    for (int i = 0; i < 5; ++i) { v[i] = xr[lane + i * 64]; ss += v[i] * v[i]; }
#pragma unroll
    for (int o = 32; o > 0; o >>= 1) ss += __shfl_xor(ss, o);
    float r = rsqrtf(ss * (1.f / DD) + EPSF);
    OT* orow = out + (size_t)row * DD;
#pragma unroll
    for (int i = 0; i < 5; ++i) orow[lane + i * 64] = (OT)(w[lane + i * 64] * v[i] * r);
}

// gather selected tokens + rmsnorm -> fp16
__global__ __launch_bounds__(256) void gather_rmsnorm_kernel(const float* __restrict__ x,
        const int* __restrict__ tkidx, const float* __restrict__ w,
        _Float16* __restrict__ out, int nrows) {
    int row = blockIdx.x * 4 + (threadIdx.x >> 6);
    int lane = threadIdx.x & 63;
    if (row >= nrows) return;
    int b = row / KK;
    int t = tkidx[row];
    const float* xr = x + ((size_t)b * SL + t) * DD;
    float v[5]; float ss = 0.f;
#pragma unroll
    for (int i = 0; i < 5; ++i) { v[i] = xr[lane + i * 64]; ss += v[i] * v[i]; }
#pragma unroll
    for (int o = 32; o > 0; o >>= 1) ss += __shfl_xor(ss, o);
    float r = rsqrtf(ss * (1.f / DD) + EPSF);
    _Float16* orow = out + (size_t)row * DD;
#pragma unroll
    for (int i = 0; i < 5; ++i) orow[lane + i * 64] = (_Float16)(w[lane + i * 64] * v[i] * r);
}

// ======================= router: sigmoid(x . rw) =======================
__global__ __launch_bounds__(256) void router_kernel(const float* __restrict__ x,
        const float* __restrict__ rw, float* __restrict__ probs, int nrows) {
    int row = blockIdx.x * 4 + (threadIdx.x >> 6);
    int lane = threadIdx.x & 63;
    if (row >= nrows) return;
    const float* xr = x + (size_t)row * DD;
    float ss = 0.f;
#pragma unroll
    for (int i = 0; i < 5; ++i) ss += xr[lane + i * 64] * rw[lane + i * 64];
#pragma unroll
    for (int o = 32; o > 0; o >>= 1) ss += __shfl_xor(ss, o);
    if (lane == 0) probs[row] = 1.f / (1.f + __expf(-ss));
}

// ======================= top-k: radix select on packed (probbits<<32 | 2047-i) ===========
__global__ __launch_bounds__(1024) void topk_kernel(const float* __restrict__ probs,
        int* __restrict__ tkidx, float* __restrict__ tkprob) {
    __shared__ int hist[256];
    __shared__ int scn[256];
    __shared__ int outc;
    __shared__ int s_digit, s_rem;
    int b = blockIdx.x, tid = threadIdx.x;
    unsigned long long k0, k1;
    {
        unsigned int f0 = __float_as_uint(probs[b * SL + tid]);
        unsigned int f1 = __float_as_uint(probs[b * SL + tid + 1024]);
        k0 = ((unsigned long long)f0 << 32) | (unsigned int)(2047 - tid);
        k1 = ((unsigned long long)f1 << 32) | (unsigned int)(2047 - (tid + 1024));
    }
    if (tid == 0) outc = 0;
    unsigned long long prefix = 0, pmask = 0;
    int target = KK;
    for (int shift = 56; shift >= 0; shift -= 8) {
        if (tid < 256) hist[tid] = 0;
        __syncthreads();
        bool a0 = (k0 & pmask) == prefix;
        bool a1 = (k1 & pmask) == prefix;
        int d0 = (int)((k0 >> shift) & 255);
        int d1 = (int)((k1 >> shift) & 255);
        if (a0) atomicAdd(&hist[d0], 1);
        if (a1) atomicAdd(&hist[d1], 1);
        __syncthreads();
        if (tid < 64) {                       // wave 0: suffix scan of 256 bins
            int h0 = hist[tid * 4], h1 = hist[tid * 4 + 1];
            int h2 = hist[tid * 4 + 2], h3 = hist[tid * 4 + 3];
            int s3 = h3, s2 = h2 + s3, s1 = h1 + s2, s0 = h0 + s1;
            int s = s0;
#pragma unroll
            for (int off = 1; off < 64; off <<= 1) {
                int v = __shfl_down(s, off);
                if (tid + off >= 64) v = 0;
                s += v;
            }
            int A = s - s0;                   // sum of later lanes' bins
            scn[tid * 4]     = s0 + A;
            scn[tid * 4 + 1] = s1 + A;
            scn[tid * 4 + 2] = s2 + A;
            scn[tid * 4 + 3] = s3 + A;
        }
        __syncthreads();
        if (tid < 256 && hist[tid] > 0) {
            int S = scn[tid];                 // count digit >= tid
            int Sgt = S - hist[tid];          // count digit >  tid
            if (Sgt < target && target <= S) { s_digit = tid; s_rem = target - Sgt; }
        }
        __syncthreads();
        int dsel = s_digit, rem = s_rem;
        bool full = (rem == hist[dsel]);
        if (a0 && (d0 > dsel || (full && d0 == dsel))) {
            int s = atomicAdd(&outc, 1);
            tkidx[b * KK + s] = 2047 - (int)(k0 & 0xffffffffu);
            tkprob[b * KK + s] = __uint_as_float((unsigned int)(k0 >> 32));
        }
        if (a1 && (d1 > dsel || (full && d1 == dsel))) {
            int s = atomicAdd(&outc, 1);
            tkidx[b * KK + s] = 2047 - (int)(k1 & 0xffffffffu);
            tkprob[b * KK + s] = __uint_as_float((unsigned int)(k1 >> 32));
        }
        if (full) break;
        target = rem;
        prefix |= ((unsigned long long)dsel) << shift;
        pmask  |= ((unsigned long long)255) << shift;
        __syncthreads();
    }
}

// ======= attention (R5 version): per-block 32 queries, 4 waves split key-tiles,
// operands direct from L2 in fragment layout, exp2 softmax with defer-max,
// zero-shuffle P->B operand (V key-permuted in the qkv epilogue), two-round combine.
__global__ __launch_bounds__(256, 2) void attn_mfma(const _Float16* __restrict__ Qh,
        const _Float16* __restrict__ Kt, const _Float16* __restrict__ Vt,
        _Float16* __restrict__ attn_out) {
    __shared__ float red[4][32][32];
    __shared__ float msh[4][32];
    __shared__ float lsh[4][32];
    int tid = threadIdx.x;
    int w = tid >> 6;
    int lane = tid & 63;
    int l31 = lane & 31, h5 = lane >> 5;
    int g = blockIdx.x;
    int j = g >> 3;
    int bh = (g & 7) + 8 * (j >> 6);     // 0..39
    int qt = 63 - (j & 63);              // longest blocks first
    int b = bh / NH, h = bh % NH;
    int nt = (qt >> 1) + 1;
    int qw = qt * 32;
    int myq = qw + l31;

    f16x8 qf[4];
    const _Float16* qrow = Qh + ((size_t)bh * SL + myq) * 64;
#pragma unroll
    for (int kd = 0; kd < 4; ++kd) qf[kd] = *(const f16x8*)(qrow + kd * 16 + h5 * 8);

    const _Float16* Kb = Kt + (size_t)bh * 32 * 4096;
    const _Float16* Vb = Vt + (size_t)bh * 32 * 4096;

    floatx16 O0, O1;
#pragma unroll
    for (int r = 0; r < 16; ++r) { O0[r] = 0.f; O1[r] = 0.f; }
    float m = -INFINITY, l = 0.f;

    for (int t = w; t < nt; t += 4) {
        const _Float16* kb = Kb + (size_t)t * 4096;
        const _Float16* vb = Vb + (size_t)t * 4096;
        f16x8 a0[4], a1[4], v0[4], v1[4];
#pragma unroll
        for (int kd = 0; kd < 4; ++kd) {
            int off = (kd * 2 + h5) * 512 + l31 * 8;
            a0[kd] = *(const f16x8*)(kb + off);
            a1[kd] = *(const f16x8*)(kb + off + 256);
        }
#pragma unroll
        for (int kc = 0; kc < 4; ++kc) {
            int off = (kc * 2 + h5) * 512 + l31 * 8;
            v0[kc] = *(const f16x8*)(vb + off);
            v1[kc] = *(const f16x8*)(vb + off + 256);
        }
        floatx16 S0, S1;
#pragma unroll
        for (int r = 0; r < 16; ++r) { S0[r] = 0.f; S1[r] = 0.f; }
#pragma unroll
        for (int kd = 0; kd < 4; ++kd) {
            S0 = __builtin_amdgcn_mfma_f32_32x32x16_f16(a0[kd], qf[kd], S0, 0, 0, 0);
            S1 = __builtin_amdgcn_mfma_f32_32x32x16_f16(a1[kd], qf[kd], S1, 0, 0, 0);
        }
        int t0 = t * 64;
        if (t0 + 63 > qw) {                  // diagonal tile: causal mask
#pragma unroll
            for (int r = 0; r < 16; ++r) {
                int key = t0 + (r & 3) + 8 * (r >> 2) + 4 * h5;
                if (key > myq) S0[r] = -INFINITY;
                if (key + 32 > myq) S1[r] = -INFINITY;
            }
        }
        float tmax = S0[0];
#pragma unroll
        for (int r = 1; r < 16; ++r) tmax = fmaxf(tmax, S0[r]);
#pragma unroll
        for (int r = 0; r < 16; ++r) tmax = fmaxf(tmax, S1[r]);
        tmax = fmaxf(tmax, __shfl_xor(tmax, 32));
        if (__any(tmax > m + 8.f)) {         // defer-max (T13)
            float mnew = fmaxf(m, tmax);
            float alpha = exp2f(m - mnew);
            l *= alpha; O0 *= alpha; O1 *= alpha; m = mnew;
        }
        float P0[16], P1[16]; float psum = 0.f;
#pragma unroll
        for (int r = 0; r < 16; ++r) { P0[r] = exp2f(S0[r] - m); psum += P0[r]; }
#pragma unroll
        for (int r = 0; r < 16; ++r) { P1[r] = exp2f(S1[r] - m); psum += P1[r]; }
        psum += __shfl_xor(psum, 32);
        l += psum;
        // PV: straight register-run P (V key-permuted to match). 16 cvt_pkrtz, 0 shuffles.
#pragma unroll
        for (int sub = 0; sub < 2; ++sub) {
            const float* P = sub ? P1 : P0;
#pragma unroll
            for (int kc = 0; kc < 2; ++kc) {
                auto q01 = __builtin_amdgcn_cvt_pkrtz(P[kc * 8 + 0], P[kc * 8 + 1]);
                auto q23 = __builtin_amdgcn_cvt_pkrtz(P[kc * 8 + 2], P[kc * 8 + 3]);
                auto q45 = __builtin_amdgcn_cvt_pkrtz(P[kc * 8 + 4], P[kc * 8 + 5]);
                auto q67 = __builtin_amdgcn_cvt_pkrtz(P[kc * 8 + 6], P[kc * 8 + 7]);
                f16x8 pf;
                pf[0] = (_Float16)q01[0]; pf[1] = (_Float16)q01[1];
                pf[2] = (_Float16)q23[0]; pf[3] = (_Float16)q23[1];
                pf[4] = (_Float16)q45[0]; pf[5] = (_Float16)q45[1];
                pf[6] = (_Float16)q67[0]; pf[7] = (_Float16)q67[1];
                int ksg = sub * 2 + kc;
                O0 = __builtin_amdgcn_mfma_f32_32x32x16_f16(v0[ksg], pf, O0, 0, 0, 0);
                O1 = __builtin_amdgcn_mfma_f32_32x32x16_f16(v1[ksg], pf, O1, 0, 0, 0);
            }
        }
    }
    // -------- cross-wave combine (two rounds over d-halves) --------
    if (h5 == 0) msh[w][l31] = m;
    __syncthreads();
    float M = fmaxf(fmaxf(msh[0][l31], msh[1][l31]), fmaxf(msh[2][l31], msh[3][l31]));
    float wgt = exp2f(m - M);                // m=-inf (idle wave) -> 0
    if (h5 == 0) lsh[w][l31] = l * wgt;
#pragma unroll
    for (int r = 0; r < 16; ++r) {
        int d = (r & 3) + 8 * (r >> 2) + 4 * h5;
        red[w][d][l31] = O0[r] * wgt;
    }
    __syncthreads();
    float lsum = lsh[0][l31] + lsh[1][l31] + lsh[2][l31] + lsh[3][l31];
    float linv = 1.f / lsum;
    if (w < 2) {
        f16x8 ov;
#pragma unroll
        for (int k = 0; k < 8; ++k) {
            int d = w * 16 + h5 * 8 + k;
            ov[k] = (_Float16)((red[0][d][l31] + red[1][d][l31] +
                                red[2][d][l31] + red[3][d][l31]) * linv);
        }
        *(f16x8*)(attn_out + ((size_t)(b * SL + myq)) * DD + h * 64 + w * 16 + h5 * 8) = ov;
    }
    __syncthreads();
#pragma unroll
    for (int r = 0; r < 16; ++r) {
        int d = (r & 3) + 8 * (r >> 2) + 4 * h5;
        red[w][d][l31] = O1[r] * wgt;
    }
    __syncthreads();
    if (w >= 2) {
        f16x8 ov;
#pragma unroll
        for (int k = 0; k < 8; ++k) {
            int d = (w - 2) * 16 + h5 * 8 + k;
            ov[k] = (_Float16)((red[0][d][l31] + red[1][d][l31] +
                                red[2][d][l31] + red[3][d][l31]) * linv);
        }
        *(f16x8*)(attn_out + ((size_t)(b * SL + myq)) * DD + h * 64 + 32 + (w - 2) * 16 + h5 * 8) = ov;
    }
}

// =========== qkv GEMM + fused RoPE/layout epilogue (prep_kernel eliminated) ===========
// 64x128 tile. Each wave's 64-aligned n-run lies in exactly one (comp, head):
//   comp 0 (q): rope pair = (acc0[r], acc1[r]) -> Qh[bh][s][d], scaled by log2e/8
//   comp 1 (k): rope -> Kt[((bh*32+t)*8+c)*512 + sl*8 + j]
//   comp 2 (v): Vt key-permuted fragment scatter (kc8/jj from key=s&63)
__global__ __launch_bounds__(256) void gemm_qkv(const _Float16* __restrict__ A,
        const _Float16* __restrict__ W, const float2* __restrict__ ropet,
        _Float16* __restrict__ Qh, _Float16* __restrict__ Kt, _Float16* __restrict__ Vt,
        int M, int N, int K, int nn_tiles) {
    __shared__ __attribute__((aligned(16))) _Float16 As[2][2048];   // [buf][kc0..3][64][8]
    __shared__ __attribute__((aligned(16))) _Float16 Ws[2][4096];   // [buf][kc0..3][128][8]
    int tid = threadIdx.x;
    int lane = tid & 63;
    int wave = tid >> 6;
    int l31 = lane & 31, h5 = lane >> 5;
    int nwg = gridDim.x;
    int q = nwg >> 3, r = nwg & 7;
    int xcd = blockIdx.x & 7, idx = blockIdx.x >> 3;
    int wgid = (xcd < r ? xcd * (q + 1) : r * (q + 1) + (xcd - r) * q) + idx;
    int mt = wgid / nn_tiles;
    int nt = wgid - mt * nn_tiles;
    int m0 = mt * 64, n0 = nt * 128;
    int wm = (wave & 1) * 32, wn2 = (wave >> 1) * 64;

    int srA = tid & 63, skA = tid >> 6;
    int srW = tid & 127, skW = tid >> 7;
    int arow = m0 + srA; if (arow >= M) arow = M - 1;
    int wrow = n0 + srW; if (wrow >= N) wrow = N - 1;
    const _Float16* Ag = A + (size_t)arow * K + skA * 8;
    const _Float16* Wg = W + (size_t)wrow * K + skW * 8;
    _Float16* AsD = As[0] + (size_t)(tid & ~63) * 8;
    _Float16* WsD = Ws[0] + (size_t)(tid & ~63) * 8;

    floatx16 acc0, acc1;
#pragma unroll
    for (int i = 0; i < 16; ++i) { acc0[i] = 0.f; acc1[i] = 0.f; }

    gll16(Ag, AsD);
    gll16(Wg, WsD);
    gll16(Wg + 16, WsD + 2048);
    __syncthreads();

    int nk = K >> 5;
    for (int t = 0; t < nk; ++t) {
        int buf = t & 1;
        if (t + 1 < nk) {
            int k0 = (t + 1) * 32;
            int bo = buf ^ 1;
            gll16(Ag + k0, AsD + bo * 2048);
            gll16(Wg + k0, WsD + bo * 4096);
            gll16(Wg + k0 + 16, WsD + bo * 4096 + 2048);
        }
        const _Float16* Asb = As[buf];
        const _Float16* Wsb = Ws[buf];
#pragma unroll
        for (int ks = 0; ks < 2; ++ks) {
            int kc = ks * 2 + h5;
            f16x8 a  = *(const f16x8*)(Asb + kc * 512 + (wm + l31) * 8);
            f16x8 b0 = *(const f16x8*)(Wsb + kc * 1024 + (wn2 + l31) * 8);
            f16x8 b1 = *(const f16x8*)(Wsb + kc * 1024 + (wn2 + 32 + l31) * 8);
            acc0 = __builtin_amdgcn_mfma_f32_32x32x16_f16(a, b0, acc0, 0, 0, 0);
            acc1 = __builtin_amdgcn_mfma_f32_32x32x16_f16(a, b1, acc1, 0, 0, 0);
        }
        __syncthreads();
    }

    // ---------------- fused epilogue ----------------
    int nb0 = n0 + wn2;                  // 64-aligned; one (comp, head) per run
    if (nb0 >= N) return;
    int comp = nb0 / DD;                 // 0=q 1=k 2=v
    int hh = (nb0 % DD) / 64;
    const float QS = 0.125f * 1.44269504088896341f;   // 1/sqrt(HD) * log2(e)
    if (comp == 2) {
#pragma unroll
        for (int r2 = 0; r2 < 16; ++r2) {
            int mm = m0 + wm + (r2 & 3) + 8 * (r2 >> 2) + 4 * h5;
            int b = mm >> 11, s = mm & 2047;
            int key = s & 63;
            int kc8 = ((key >> 4) << 1) | ((key >> 2) & 1);
            int jj = (key & 3) | (((key >> 3) & 1) << 2);
            size_t vbase = (((size_t)(b * NH + hh) * 32 + (s >> 6)) * 8 + kc8) * 512 + jj;
            Vt[vbase + (size_t)l31 * 8] = (_Float16)acc0[r2];
            Vt[vbase + (size_t)(l31 + 32) * 8] = (_Float16)acc1[r2];
        }
    } else {
#pragma unroll
        for (int r2 = 0; r2 < 16; ++r2) {
            int mm = m0 + wm + (r2 & 3) + 8 * (r2 >> 2) + 4 * h5;
            int b = mm >> 11, s = mm & 2047;
            float2 cs = ropet[(size_t)s * 32 + l31];
            float lo = acc0[r2], hi = acc1[r2];
            float ro0 = lo * cs.x - hi * cs.y;       // d = l31 (< 32)
            float ro1 = hi * cs.x + lo * cs.y;       // d = l31 + 32
            if (comp == 0) {
                _Float16* qp = Qh + ((size_t)(b * NH + hh) * SL + s) * 64;
                qp[l31] = (_Float16)(ro0 * QS);
                qp[l31 + 32] = (_Float16)(ro1 * QS);
            } else {
                size_t kb2 = (((size_t)(b * NH + hh) * 32 + (s >> 6)) * 8) * 512 + (s & 63) * 8;
                Kt[kb2 + (size_t)(l31 >> 3) * 512 + (l31 & 7)] = (_Float16)ro0;
                Kt[kb2 + (size_t)((l31 + 32) >> 3) * 512 + (l31 & 7)] = (_Float16)ro1;
            }
        }
    }
}

// ======================= MFMA GEMM: 64x64 tile, BK=64 (4 MFMA/barrier) ==========
// MODE 1: X += acc (fp32)   MODE 2: X[(b*SL+sidx[m])*N+n] += acc*sprob[m]
template<int MODE>
__global__ __launch_bounds__(256) void gemm_mfma(const _Float16* __restrict__ A,
        const _Float16* __restrict__ W, _Float16* __restrict__ Ch, float* __restrict__ X,
        int M, int N, int K, int nn_tiles, const int* __restrict__ sidx, const float* __restrict__ sprob) {
    __shared__ __attribute__((aligned(16))) _Float16 As[2][4096];   // [buf][kc0..7][64][8]
    __shared__ __attribute__((aligned(16))) _Float16 Ws[2][4096];
    int tid = threadIdx.x;
    int lane = tid & 63;
    int wave = tid >> 6;
    int l31 = lane & 31, h5 = lane >> 5;
    int nwg = gridDim.x;
    int q = nwg >> 3, r = nwg & 7;
    int xcd = blockIdx.x & 7, idx = blockIdx.x >> 3;
    int wgid = (xcd < r ? xcd * (q + 1) : r * (q + 1) + (xcd - r) * q) + idx;
    int mt = wgid / nn_tiles;
    int nt = wgid - mt * nn_tiles;
    int m0 = mt * 64, n0 = nt * 64;
    int wm = (wave & 1) * 32, wn = (wave >> 1) * 32;

    int srow = tid & 63;
    int skc = tid >> 6;          // 0..3
    int arow = m0 + srow; if (arow >= M) arow = M - 1;
    int wrow = n0 + srow; if (wrow >= N) wrow = N - 1;
    const _Float16* Ag = A + (size_t)arow * K + skc * 8;
    const _Float16* Wg = W + (size_t)wrow * K + skc * 8;
    _Float16* AsD = As[0] + (size_t)(tid & ~63) * 8;
    _Float16* WsD = Ws[0] + (size_t)(tid & ~63) * 8;

    floatx16 acc;
#pragma unroll
    for (int i = 0; i < 16; ++i) acc[i] = 0.f;

    int nk32 = K >> 5;
    int nfull = nk32 >> 1;
    int tail = nk32 & 1;

    gll16(Ag, AsD);
    gll16(Wg, WsD);
    gll16(Ag + 32, AsD + 2048);
    gll16(Wg + 32, WsD + 2048);
    __syncthreads();

    for (int t = 0; t < nfull; ++t) {
        int buf = t & 1;
        int bo = (buf ^ 1) * 4096;
        if (t + 1 < nfull) {
            int k0 = (t + 1) * 64;
            gll16(Ag + k0, AsD + bo);
            gll16(Wg + k0, WsD + bo);
            gll16(Ag + k0 + 32, AsD + bo + 2048);
            gll16(Wg + k0 + 32, WsD + bo + 2048);
        } else if (tail) {
            int k0 = nfull * 64;
            gll16(Ag + k0, AsD + bo);
            gll16(Wg + k0, WsD + bo);
        }
        const _Float16* Asb = As[buf];
        const _Float16* Wsb = Ws[buf];
#pragma unroll
        for (int ks = 0; ks < 4; ++ks) {
            int kc = ks * 2 + h5;
            f16x8 a = *(const f16x8*)(Asb + kc * 512 + (wm + l31) * 8);
            f16x8 b = *(const f16x8*)(Wsb + kc * 512 + (wn + l31) * 8);
            acc = __builtin_amdgcn_mfma_f32_32x32x16_f16(a, b, acc, 0, 0, 0);
        }
        __syncthreads();
    }
    if (tail) {
        int buf = nfull & 1;
        const _Float16* Asb = As[buf];
        const _Float16* Wsb = Ws[buf];
#pragma unroll
        for (int ks = 0; ks < 2; ++ks) {
            int kc = ks * 2 + h5;
            f16x8 a = *(const f16x8*)(Asb + kc * 512 + (wm + l31) * 8);
            f16x8 b = *(const f16x8*)(Wsb + kc * 512 + (wn + l31) * 8);
            acc = __builtin_amdgcn_mfma_f32_32x32x16_f16(a, b, acc, 0, 0, 0);
        }
    }

    int nn = n0 + wn + l31;
#pragma unroll
    for (int r2 = 0; r2 < 16; ++r2) {
        int mm = m0 + wm + (r2 & 3) + 8 * (r2 >> 2) + 4 * h5;
        if (mm >= M || nn >= N) continue;
        float v = acc[r2];
        if (MODE == 1) {
            X[(size_t)mm * N + nn] += v;
        } else {
            int b = mm / KK;
            X[((size_t)(b * SL + sidx[mm])) * N + nn] += v * sprob[mm];
        }
    }
}

// ============ fused gate+up GEMM: 64x128 tile (8 MFMA + 5 staging per barrier) ========
__global__ __launch_bounds__(256) void gemm_gateup(const _Float16* __restrict__ A,
        const _Float16* __restrict__ Wg, const _Float16* __restrict__ Wu,
        _Float16* __restrict__ Ch, int M, int N, int K, int nn_tiles) {
    __shared__ __attribute__((aligned(16))) _Float16 As[2][2048];
    __shared__ __attribute__((aligned(16))) _Float16 Wgs[2][4096];
    __shared__ __attribute__((aligned(16))) _Float16 Wus[2][4096];
    int tid = threadIdx.x;
    int lane = tid & 63;
    int wave = tid >> 6;
    int l31 = lane & 31, h5 = lane >> 5;
    int nwg = gridDim.x;
    int q = nwg >> 3, r = nwg & 7;
    int xcd = blockIdx.x & 7, idx = blockIdx.x >> 3;
    int wgid = (xcd < r ? xcd * (q + 1) : r * (q + 1) + (xcd - r) * q) + idx;
    int mt = wgid / nn_tiles;
    int nt = wgid - mt * nn_tiles;
    int m0 = mt * 64, n0 = nt * 128;
    int wm = (wave & 1) * 32, wn2 = (wave >> 1) * 64;

    int srA = tid & 63, skA = tid >> 6;
    int srW = tid & 127, skW = tid >> 7;
    int arow = m0 + srA; if (arow >= M) arow = M - 1;
    int wrow = n0 + srW; if (wrow >= N) wrow = N - 1;
    const _Float16* Ag  = A  + (size_t)arow * K + skA * 8;
    const _Float16* Wgg = Wg + (size_t)wrow * K + skW * 8;
    const _Float16* Wug = Wu + (size_t)wrow * K + skW * 8;
    _Float16* AsD  = As[0]  + (size_t)(tid & ~63) * 8;
    _Float16* WgsD = Wgs[0] + (size_t)(tid & ~63) * 8;
    _Float16* WusD = Wus[0] + (size_t)(tid & ~63) * 8;

    floatx16 ag0, ag1, au0, au1;
#pragma unroll
    for (int i = 0; i < 16; ++i) { ag0[i] = 0.f; ag1[i] = 0.f; au0[i] = 0.f; au1[i] = 0.f; }

    gll16(Ag, AsD);
    gll16(Wgg, WgsD);
    gll16(Wgg + 16, WgsD + 2048);
    gll16(Wug, WusD);
    gll16(Wug + 16, WusD + 2048);
    __syncthreads();

    int nk = K >> 5;
    for (int t = 0; t < nk; ++t) {
        int buf = t & 1;
        if (t + 1 < nk) {
            int k0 = (t + 1) * 32;
            int bo = buf ^ 1;
            gll16(Ag + k0, AsD + bo * 2048);
            gll16(Wgg + k0, WgsD + bo * 4096);
            gll16(Wgg + k0 + 16, WgsD + bo * 4096 + 2048);
            gll16(Wug + k0, WusD + bo * 4096);
            gll16(Wug + k0 + 16, WusD + bo * 4096 + 2048);
        }
        const _Float16* Asb = As[buf];
        const _Float16* Wgb = Wgs[buf];
        const _Float16* Wub = Wus[buf];
#pragma unroll
        for (int ks = 0; ks < 2; ++ks) {
            int kc = ks * 2 + h5;
            f16x8 a  = *(const f16x8*)(Asb + kc * 512 + (wm + l31) * 8);
            f16x8 g0 = *(const f16x8*)(Wgb + kc * 1024 + (wn2 + l31) * 8);
            f16x8 g1 = *(const f16x8*)(Wgb + kc * 1024 + (wn2 + 32 + l31) * 8);
            f16x8 u0 = *(const f16x8*)(Wub + kc * 1024 + (wn2 + l31) * 8);
            f16x8 u1 = *(const f16x8*)(Wub + kc * 1024 + (wn2 + 32 + l31) * 8);
            ag0 = __builtin_amdgcn_mfma_f32_32x32x16_f16(a, g0, ag0, 0, 0, 0);
            au0 = __builtin_amdgcn_mfma_f32_32x32x16_f16(a, u0, au0, 0, 0, 0);
            ag1 = __builtin_amdgcn_mfma_f32_32x32x16_f16(a, g1, ag1, 0, 0, 0);
            au1 = __builtin_amdgcn_mfma_f32_32x32x16_f16(a, u1, au1, 0, 0, 0);
        }
        __syncthreads();
    }

#pragma unroll
    for (int nj = 0; nj < 2; ++nj) {
        int nn = n0 + wn2 + nj * 32 + l31;
        if (nn >= N) continue;
        const floatx16& gA = nj ? ag1 : ag0;
        const floatx16& uA = nj ? au1 : au0;
#pragma unroll
        for (int r2 = 0; r2 < 16; ++r2) {
            int mm = m0 + wm + (r2 & 3) + 8 * (r2 >> 2) + 4 * h5;
            if (mm >= M) continue;
            float gv = gA[r2], uv = uA[r2];
            Ch[(size_t)mm * N + nn] = (_Float16)((gv / (1.f + __expf(-gv))) * uv);
        }
    }
}

// ======================= launch =======================
extern "C" void kernel_launch(void* const* d_in, const int* in_sizes, int n_in,
                              void* d_out, int out_size, void* d_ws, size_t ws_size,
                              hipStream_t stream) {
    const int*   ids          = (const int*)d_in[0];
    const int*   iter         = (const int*)d_in[1];
    const float* emb          = (const float*)d_in[2];
    const float* iter_emb     = (const float*)d_in[3];
    const float* attn_norm_w  = (const float*)d_in[4];
    const float* Wqkv         = (const float*)d_in[5];
    const float* wo_w         = (const float*)d_in[6];
    const float* router_w     = (const float*)d_in[7];
    const float* mlp_norm_w   = (const float*)d_in[8];
    const float* gate_w       = (const float*)d_in[9];
    const float* up_w         = (const float*)d_in[10];
    const float* down_w       = (const float*)d_in[11];
    const float* final_norm_w = (const float*)d_in[12];
    float* out = (float*)d_out;

    const size_t XN   = (size_t)BB * SL * DD;        // 5,242,880
    const size_t QKVN = (size_t)BB * SL * 3 * DD;    // 15,728,640
    const size_t HN   = (size_t)BB * NH * SL * 64;   // 5,242,880
    char* ws = (char*)d_ws;
    size_t off = 0;
    float*    x        = (float*)(ws + off);    off += XN * 4;
    _Float16* h        = (_Float16*)(ws + off); off += XN * 2;
    _Float16* attn_out = (_Float16*)(ws + off); off += XN * 2;
    float*    probs    = (float*)(ws + off);    off += (size_t)BB * SL * 4;
    int*      tkidx    = (int*)(ws + off);      off += (size_t)BB * KK * 4;
    float*    tkprob   = (float*)(ws + off);    off += (size_t)BB * KK * 4;
    off = (off + 255) & ~(size_t)255;
    _Float16* qkvh     = (_Float16*)(ws + off); off += QKVN * 2;   // g1 buffer (gateup out)
    _Float16* Qh       = (_Float16*)(ws + off); off += HN * 2;
    _Float16* Kh       = (_Float16*)(ws + off); off += HN * 2;
    _Float16* Vh       = (_Float16*)(ws + off); off += HN * 2;
    float2*   ropet    = (float2*)(ws + off);   off += (size_t)SL * 32 * 8;   // 512 KB
    _Float16* WqkvH    = (_Float16*)(ws + off);
    _Float16* woH   = WqkvH + (size_t)NL * 3 * DD * DD;
    _Float16* gateH = woH   + (size_t)NL * DD * DD;
    _Float16* upH   = gateH + (size_t)NL * FF * DD;
    _Float16* downH = upH   + (size_t)NL * FF * DD;
    _Float16* g1 = qkvh;

    rope_init_kernel<<<SL * 32 / 256, 256, 0, stream>>>(ropet);
    {
        int n1 = NL * 3 * DD * DD / 4, n2 = NL * DD * DD / 4;
        int n3 = NL * FF * DD / 4, n4 = NL * FF * DD / 4, n5 = NL * DD * FF / 4;
        int ntot = n1 + n2 + n3 + n4 + n5;
        cast5_kernel<<<(ntot + 255) / 256, 256, 0, stream>>>(
            Wqkv, wo_w, gate_w, up_w, down_w,
            WqkvH, woH, gateH, upH, downH, n1, n2, n3, n4, n5);
    }

    embed_kernel<<<20480, 256, 0, stream>>>(ids, iter, emb, iter_emb, x);

    const int M1 = BB * SL;    // 16384
    const int M2 = BB * KK;    // 13104
    const int MT1 = (M1 + 63) / 64;    // 256
    const int MT2 = (M2 + 63) / 64;    // 205
    for (int l = 0; l < NL; ++l) {
        rmsnorm_kernel<_Float16><<<4096, 256, 0, stream>>>(x, attn_norm_w + l * DD, h, M1);
        gemm_qkv<<<MT1 * 8, 256, 0, stream>>>(h, WqkvH + (size_t)l * 3 * DD * DD,
                                              ropet, Qh, Kh, Vh, M1, 3 * DD, DD, 8);
        attn_mfma<<<BB * NH * (SL / 32), 256, 0, stream>>>(Qh, Kh, Vh, attn_out);
        gemm_mfma<1><<<MT1 * 5, 256, 0, stream>>>(attn_out, woH + (size_t)l * DD * DD,
                                                  nullptr, x, M1, DD, DD, 5, nullptr, nullptr);
        router_kernel<<<4096, 256, 0, stream>>>(x, router_w + l * DD, probs, M1);
        topk_kernel<<<BB, 1024, 0, stream>>>(probs, tkidx, tkprob);
        gather_rmsnorm_kernel<<<3276, 256, 0, stream>>>(x, tkidx, mlp_norm_w + l * DD, h, M2);
        gemm_gateup<<<MT2 * 7, 256, 0, stream>>>(h, gateH + (size_t)l * FF * DD,
                                                 upH + (size_t)l * FF * DD, g1, M2, FF, DD, 7);
        gemm_mfma<2><<<MT2 * 5, 256, 0, stream>>>(g1, downH + (size_t)l * DD * FF,
                                                  nullptr, x, M2, DD, FF, 5, tkidx, tkprob);
    }
    rmsnorm_kernel<float><<<4096, 256, 0, stream>>>(x, final_norm_w, out, M1);
}